// Round 1
// baseline (1964.542 us; speedup 1.0000x reference)
//
#include <hip/hip_runtime.h>
#include <hip/hip_bf16.h>
#include <cstddef>

#define B_      4
#define N_      1024
#define DIM_    512
#define H_      8
#define D_      64
#define INNER_  512
#define TRIPLE_ 1536
#define KK_     716        // int(1024 * 0.7)
#define SCALE_  0.125f     // 64^-0.5

// ---------------------------------------------------------------------------
// fp32 tiled GEMM: C[M,Nn] = A[M,K] @ B[K,Nn] (+ bias). 64x64 tile, 256 thr,
// 4x4 microtile per thread, BK=16.
// ---------------------------------------------------------------------------
template <int M, int Nn, int K, bool BIAS>
__global__ __launch_bounds__(256) void gemm_f32(const float* __restrict__ A,
                                                const float* __restrict__ Bm,
                                                const float* __restrict__ bias,
                                                float* __restrict__ C) {
    __shared__ float As[16][64];   // [k][m]
    __shared__ float Bs[16][64];   // [k][n]
    const int t  = threadIdx.x;
    const int n0 = blockIdx.x * 64;
    const int m0 = blockIdx.y * 64;
    const int tn = t & 15, tm = t >> 4;
    const int lm = t >> 2;          // A-load row 0..63
    const int lk = (t & 3) * 4;     // A-load k 0,4,8,12
    const int wk = t >> 4;          // B-load k 0..15
    const int wn = (t & 15) * 4;    // B-load col

    float acc[4][4] = {};

    for (int k0 = 0; k0 < K; k0 += 16) {
        float4 av = *(const float4*)&A[(size_t)(m0 + lm) * K + k0 + lk];
        As[lk + 0][lm] = av.x;
        As[lk + 1][lm] = av.y;
        As[lk + 2][lm] = av.z;
        As[lk + 3][lm] = av.w;
        *(float4*)&Bs[wk][wn] = *(const float4*)&Bm[(size_t)(k0 + wk) * Nn + n0 + wn];
        __syncthreads();
#pragma unroll
        for (int k = 0; k < 16; ++k) {
            float4 a4 = *(const float4*)&As[k][tm * 4];
            float4 b4 = *(const float4*)&Bs[k][tn * 4];
            float aa[4] = {a4.x, a4.y, a4.z, a4.w};
            float bb[4] = {b4.x, b4.y, b4.z, b4.w};
#pragma unroll
            for (int i = 0; i < 4; ++i)
#pragma unroll
                for (int j = 0; j < 4; ++j) acc[i][j] += aa[i] * bb[j];
        }
        __syncthreads();
    }

    float4 bv = make_float4(0.f, 0.f, 0.f, 0.f);
    if (BIAS) bv = *(const float4*)&bias[n0 + tn * 4];
#pragma unroll
    for (int i = 0; i < 4; ++i) {
        int row = m0 + tm * 4 + i;
        float4 o = make_float4(acc[i][0] + bv.x, acc[i][1] + bv.y,
                               acc[i][2] + bv.z, acc[i][3] + bv.w);
        *(float4*)&C[(size_t)row * Nn + n0 + tn * 4] = o;
    }
}

// order-preserving float->uint key (descending float == descending uint)
__device__ __forceinline__ unsigned f2key(float f) {
    unsigned u = __float_as_uint(f);
    return u ^ ((u & 0x80000000u) ? 0xFFFFFFFFu : 0x80000000u);
}
__device__ __forceinline__ float key2f(unsigned k) {
    unsigned u = (k & 0x80000000u) ? (k ^ 0x80000000u) : ~k;
    return __uint_as_float(u);
}

// ---------------------------------------------------------------------------
// Fused kNN attention: one workgroup = (b, h, 8 query rows).
// dots row-block in LDS; exact top-k threshold by per-wave binary search on
// ordered uint keys; softmax; PV accumulate; write attn_out [B,N,INNER].
// ---------------------------------------------------------------------------
__global__ __launch_bounds__(256) void attn_kernel(const float* __restrict__ qkv,
                                                   float* __restrict__ attn_out) {
    __shared__ float    sdots[8][N_];   // 32 KB: dots, later p
    __shared__ float    sq[8][D_];      // 2 KB
    __shared__ unsigned sthr[8];
    __shared__ float    smax[8], ssum[8];

    const int t  = threadIdx.x;
    const int wg = blockIdx.x;
    const int bh = wg >> 7;            // 0..31
    const int i0 = (wg & 127) * 8;
    const int b  = bh >> 3, h = bh & 7;

    // ---- load q rows into LDS
    for (int e = t; e < 8 * D_; e += 256) {
        int r = e >> 6, d = e & 63;
        sq[r][d] = qkv[(size_t)(b * N_ + i0 + r) * TRIPLE_ + h * D_ + d];
    }
    __syncthreads();

    // ---- dots: thread owns (row r, 32 columns)
    {
        const int r = t >> 5, jl = t & 31;
        float qreg[64];
#pragma unroll
        for (int d = 0; d < 64; d += 4) {
            float4 qv = *(const float4*)&sq[r][d];
            qreg[d] = qv.x; qreg[d + 1] = qv.y; qreg[d + 2] = qv.z; qreg[d + 3] = qv.w;
        }
        for (int jt = 0; jt < 32; ++jt) {
            int j = jt * 32 + jl;
            const float4* kp =
                (const float4*)&qkv[(size_t)(b * N_ + j) * TRIPLE_ + INNER_ + h * D_];
            float acc = 0.f;
#pragma unroll
            for (int dq = 0; dq < 16; ++dq) {
                float4 kv = kp[dq];
                acc += qreg[4 * dq + 0] * kv.x + qreg[4 * dq + 1] * kv.y +
                       qreg[4 * dq + 2] * kv.z + qreg[4 * dq + 3] * kv.w;
            }
            sdots[r][j] = acc * SCALE_;
        }
    }
    __syncthreads();

    // ---- exact kth-largest per row: wave w handles rows 2w, 2w+1
    {
        const int w = t >> 6, l = t & 63;
        for (int rr = 0; rr < 2; ++rr) {
            const int r = w * 2 + rr;
            unsigned key[16];
            unsigned kmax = 0u;
#pragma unroll
            for (int m = 0; m < 16; ++m) {
                unsigned u = f2key(sdots[r][l + 64 * m]);
                key[m] = u;
                kmax   = kmax > u ? kmax : u;
            }
#pragma unroll
            for (int off = 32; off > 0; off >>= 1) {
                unsigned o = __shfl_xor(kmax, off, 64);
                kmax = kmax > o ? kmax : o;
            }
            unsigned res = 0u;
            for (int bit = 31; bit >= 0; --bit) {
                unsigned trial = res | (1u << bit);
                int c = 0;
#pragma unroll
                for (int m = 0; m < 16; ++m) c += (key[m] >= trial) ? 1 : 0;
#pragma unroll
                for (int off = 32; off > 0; off >>= 1) c += __shfl_xor(c, off, 64);
                if (c >= KK_) res = trial;   // wave-uniform
            }
            if (l == 0) {
                sthr[r] = res;
                smax[r] = key2f(kmax);
            }
        }
    }
    __syncthreads();

    // ---- weights p = keep ? exp(x - max) : 0 ; row sums
    {
        const int r = t >> 5, jl = t & 31;
        const unsigned thr = sthr[r];
        const float    m   = smax[r];
        float lsum = 0.f;
        for (int jt = 0; jt < 32; ++jt) {
            int   j = jt * 32 + jl;
            float x = sdots[r][j];
            float p = (f2key(x) >= thr) ? __expf(x - m) : 0.f;
            sdots[r][j] = p;
            lsum += p;
        }
#pragma unroll
        for (int off = 16; off > 0; off >>= 1) lsum += __shfl_xor(lsum, off, 64);
        if (jl == 0) ssum[r] = lsum;
    }
    __syncthreads();

    // ---- PV: thread owns (row r, dims 2d, 2d+1)
    {
        const int r  = t >> 5;
        const int dd = (t & 31) * 2;
        const float inv = 1.f / ssum[r];
        const float* vbase = &qkv[(size_t)(b * N_) * TRIPLE_ + 2 * INNER_ + h * D_];
        float acc0 = 0.f, acc1 = 0.f;
#pragma unroll 4
        for (int j = 0; j < N_; ++j) {
            float  p  = sdots[r][j];
            float2 vv = *(const float2*)&vbase[(size_t)j * TRIPLE_ + dd];
            acc0 += p * vv.x;
            acc1 += p * vv.y;
        }
        float* o = &attn_out[(size_t)(b * N_ + i0 + r) * INNER_ + h * D_];
        *(float2*)&o[dd] = make_float2(acc0 * inv, acc1 * inv);
    }
}

extern "C" void kernel_launch(void* const* d_in, const int* in_sizes, int n_in,
                              void* d_out, int out_size, void* d_ws, size_t ws_size,
                              hipStream_t stream) {
    const float* x     = (const float*)d_in[0];
    const float* w_qkv = (const float*)d_in[1];
    const float* w_out = (const float*)d_in[2];
    const float* b_out = (const float*)d_in[3];
    float*       out   = (float*)d_out;

    float* qkv      = (float*)d_ws;                          // 4*1024*1536 fp32 = 25.2 MB
    float* attn_out = qkv + (size_t)B_ * N_ * TRIPLE_;       // 4*1024*512  fp32 =  8.4 MB

    // qkv projection: [4096,512] @ [512,1536]
    gemm_f32<B_ * N_, TRIPLE_, DIM_, false>
        <<<dim3(TRIPLE_ / 64, (B_ * N_) / 64), 256, 0, stream>>>(x, w_qkv, nullptr, qkv);

    // fused kNN attention
    attn_kernel<<<dim3(B_ * H_ * (N_ / 8)), 256, 0, stream>>>(qkv, attn_out);

    // output projection: [4096,512] @ [512,512] + bias
    gemm_f32<B_ * N_, DIM_, INNER_, true>
        <<<dim3(DIM_ / 64, (B_ * N_) / 64), 256, 0, stream>>>(attn_out, w_out, b_out, out);
}

// Round 2
// 441.209 us; speedup vs baseline: 4.4526x; 4.4526x over previous
//
#include <hip/hip_runtime.h>
#include <cstddef>

#define B_      4
#define N_      1024
#define DIM_    512
#define H_      8
#define D_      64
#define INNER_  512
#define TRIPLE_ 1536
#define KK_     716        // int(1024 * 0.7)
#define SCALE_  0.125f     // 64^-0.5

typedef short bf16x8 __attribute__((ext_vector_type(8)));
typedef float f32x4  __attribute__((ext_vector_type(4)));

__device__ __forceinline__ unsigned short bf16_rne(float f) {
    unsigned u = __float_as_uint(f);
    return (unsigned short)((u + 0x7FFFu + ((u >> 16) & 1u)) >> 16);
}
__device__ __forceinline__ float bf16_f(unsigned short s) {
    return __uint_as_float((unsigned)s << 16);
}
// order-preserving float->uint key (descending float == descending uint)
__device__ __forceinline__ unsigned f2key(float f) {
    unsigned u = __float_as_uint(f);
    return u ^ ((u & 0x80000000u) ? 0xFFFFFFFFu : 0x80000000u);
}
__device__ __forceinline__ float key2f(unsigned k) {
    unsigned u = (k & 0x80000000u) ? (k ^ 0x80000000u) : ~k;
    return __uint_as_float(u);
}

// ---------------------------------------------------------------------------
// fp32 tiled GEMM (used for out-proj): C[M,Nn] = A[M,K] @ B[K,Nn] (+ bias).
// ---------------------------------------------------------------------------
template <int M, int Nn, int K, bool BIAS>
__global__ __launch_bounds__(256) void gemm_f32(const float* __restrict__ A,
                                                const float* __restrict__ Bm,
                                                const float* __restrict__ bias,
                                                float* __restrict__ C) {
    __shared__ float As[16][64];   // [k][m]
    __shared__ float Bs[16][64];   // [k][n]
    const int t  = threadIdx.x;
    const int n0 = blockIdx.x * 64;
    const int m0 = blockIdx.y * 64;
    const int tn = t & 15, tm = t >> 4;
    const int lm = t >> 2;
    const int lk = (t & 3) * 4;
    const int wk = t >> 4;
    const int wn = (t & 15) * 4;

    float acc[4][4] = {};

    for (int k0 = 0; k0 < K; k0 += 16) {
        float4 av = *(const float4*)&A[(size_t)(m0 + lm) * K + k0 + lk];
        As[lk + 0][lm] = av.x;
        As[lk + 1][lm] = av.y;
        As[lk + 2][lm] = av.z;
        As[lk + 3][lm] = av.w;
        *(float4*)&Bs[wk][wn] = *(const float4*)&Bm[(size_t)(k0 + wk) * Nn + n0 + wn];
        __syncthreads();
#pragma unroll
        for (int k = 0; k < 16; ++k) {
            float4 a4 = *(const float4*)&As[k][tm * 4];
            float4 b4 = *(const float4*)&Bs[k][tn * 4];
            float aa[4] = {a4.x, a4.y, a4.z, a4.w};
            float bb[4] = {b4.x, b4.y, b4.z, b4.w};
#pragma unroll
            for (int i = 0; i < 4; ++i)
#pragma unroll
                for (int j = 0; j < 4; ++j) acc[i][j] += aa[i] * bb[j];
        }
        __syncthreads();
    }

    float4 bv = make_float4(0.f, 0.f, 0.f, 0.f);
    if (BIAS) bv = *(const float4*)&bias[n0 + tn * 4];
#pragma unroll
    for (int i = 0; i < 4; ++i) {
        int row = m0 + tm * 4 + i;
        float4 o = make_float4(acc[i][0] + bv.x, acc[i][1] + bv.y,
                               acc[i][2] + bv.z, acc[i][3] + bv.w);
        *(float4*)&C[(size_t)row * Nn + n0 + tn * 4] = o;
    }
}

// ---------------------------------------------------------------------------
// qkv GEMM: [4096,512] @ [512,1536], fp32 accumulate; epilogue splits q,k into
// hi/lo bf16 [bh][n][64] and writes v transposed bf16 [bh][d][1024].
// ---------------------------------------------------------------------------
__global__ __launch_bounds__(256) void gemm_qkv(const float* __restrict__ A,
                                                const float* __restrict__ Bm,
                                                unsigned short* __restrict__ Qh,
                                                unsigned short* __restrict__ Ql,
                                                unsigned short* __restrict__ Kh,
                                                unsigned short* __restrict__ Kl,
                                                unsigned short* __restrict__ Vt) {
    __shared__ float As[16][64];
    __shared__ float Bs[16][64];
    const int t  = threadIdx.x;
    const int n0 = blockIdx.x * 64;
    const int m0 = blockIdx.y * 64;
    const int tn = t & 15, tm = t >> 4;
    const int lm = t >> 2;
    const int lk = (t & 3) * 4;
    const int wk = t >> 4;
    const int wn = (t & 15) * 4;

    float acc[4][4] = {};

    for (int k0 = 0; k0 < DIM_; k0 += 16) {
        float4 av = *(const float4*)&A[(size_t)(m0 + lm) * DIM_ + k0 + lk];
        As[lk + 0][lm] = av.x;
        As[lk + 1][lm] = av.y;
        As[lk + 2][lm] = av.z;
        As[lk + 3][lm] = av.w;
        *(float4*)&Bs[wk][wn] = *(const float4*)&Bm[(size_t)(k0 + wk) * TRIPLE_ + n0 + wn];
        __syncthreads();
#pragma unroll
        for (int k = 0; k < 16; ++k) {
            float4 a4 = *(const float4*)&As[k][tm * 4];
            float4 b4 = *(const float4*)&Bs[k][tn * 4];
            float aa[4] = {a4.x, a4.y, a4.z, a4.w};
            float bb[4] = {b4.x, b4.y, b4.z, b4.w};
#pragma unroll
            for (int i = 0; i < 4; ++i)
#pragma unroll
                for (int j = 0; j < 4; ++j) acc[i][j] += aa[i] * bb[j];
        }
        __syncthreads();
    }

    const int sec = n0 >> 9;           // 0=q, 1=k, 2=v (uniform per block)
    const int h   = (n0 >> 6) & 7;
    const int d0  = tn * 4;
#pragma unroll
    for (int i = 0; i < 4; ++i) {
        const int row = m0 + tm * 4 + i;
        const int b = row >> 10, nn = row & 1023;
        if (sec < 2) {
            unsigned short* Hp = sec ? Kh : Qh;
            unsigned short* Lp = sec ? Kl : Ql;
            size_t base = (((size_t)(b * 8 + h) << 10) + nn) * 64 + d0;
            unsigned short hv[4], lv[4];
#pragma unroll
            for (int j = 0; j < 4; ++j) {
                float v = acc[i][j];
                unsigned short hb = bf16_rne(v);
                hv[j] = hb;
                lv[j] = bf16_rne(v - bf16_f(hb));
            }
            *(ushort4*)&Hp[base] = make_ushort4(hv[0], hv[1], hv[2], hv[3]);
            *(ushort4*)&Lp[base] = make_ushort4(lv[0], lv[1], lv[2], lv[3]);
        } else {
#pragma unroll
            for (int j = 0; j < 4; ++j)
                Vt[(((size_t)(b * 8 + h) << 6) + d0 + j) * 1024 + nn] = bf16_rne(acc[i][j]);
        }
    }
}

// ---------------------------------------------------------------------------
// MFMA kNN attention. WG = 256 thr (4 waves) = (b,h, 16 q-rows).
// Phase 1: dots = (qh+ql)(kh+kl)^T via 3 split-bf16 products -> fp32 LDS.
// Phase 2: exact top-k threshold (binary search on ordered uint keys),
//          softmax, normalized p back into LDS.
// Phase 3: P @ V via bf16 MFMA, V read as Vt[d][j] fragments from global.
// sdots is XOR-swizzled (per-row (r&7)<<2) to avoid phase-3 b128 conflicts.
// ---------------------------------------------------------------------------
__global__ __launch_bounds__(256) void attn_mfma(const unsigned short* __restrict__ Qh,
                                                 const unsigned short* __restrict__ Ql,
                                                 const unsigned short* __restrict__ Kh,
                                                 const unsigned short* __restrict__ Kl,
                                                 const unsigned short* __restrict__ Vt,
                                                 float* __restrict__ attn_out) {
    __shared__ float sdots[16 * 1024];   // exactly 64 KB

    const int t    = threadIdx.x;
    const int w    = t >> 6;        // wave 0..3
    const int l    = t & 63;        // lane
    const int ln   = l & 15;
    const int quad = l >> 4;
    const int wg   = blockIdx.x;
    const int bh   = wg >> 6;       // 0..31
    const int i0   = (wg & 63) << 4;

    const size_t bhoff = (size_t)bh << 16;   // bh*1024*64

    // ---- Q fragments (A-operand: m=ln -> row, k=quad*8+t -> d)
    const unsigned short* qp  = Qh + bhoff + (size_t)(i0 + ln) * 64 + (quad << 3);
    const unsigned short* qlp = Ql + bhoff + (size_t)(i0 + ln) * 64 + (quad << 3);
    bf16x8 qh0 = *(const bf16x8*)qp;
    bf16x8 qh1 = *(const bf16x8*)(qp + 32);
    bf16x8 ql0 = *(const bf16x8*)qlp;
    bf16x8 ql1 = *(const bf16x8*)(qlp + 32);

    // ---- Phase 1: dots. wave w covers j in [w*256, w*256+256)
    for (int tt = 0; tt < 16; ++tt) {
        const int j0 = ((w << 4) + tt) << 4;
        const unsigned short* kp  = Kh + bhoff + (size_t)(j0 + ln) * 64 + (quad << 3);
        const unsigned short* klp = Kl + bhoff + (size_t)(j0 + ln) * 64 + (quad << 3);
        bf16x8 kh0 = *(const bf16x8*)kp;
        bf16x8 kh1 = *(const bf16x8*)(kp + 32);
        bf16x8 kl0 = *(const bf16x8*)klp;
        bf16x8 kl1 = *(const bf16x8*)(klp + 32);
        f32x4 acc = {0.f, 0.f, 0.f, 0.f};
        acc = __builtin_amdgcn_mfma_f32_16x16x32_bf16(qh0, kh0, acc, 0, 0, 0);
        acc = __builtin_amdgcn_mfma_f32_16x16x32_bf16(qh1, kh1, acc, 0, 0, 0);
        acc = __builtin_amdgcn_mfma_f32_16x16x32_bf16(qh0, kl0, acc, 0, 0, 0);
        acc = __builtin_amdgcn_mfma_f32_16x16x32_bf16(qh1, kl1, acc, 0, 0, 0);
        acc = __builtin_amdgcn_mfma_f32_16x16x32_bf16(ql0, kh0, acc, 0, 0, 0);
        acc = __builtin_amdgcn_mfma_f32_16x16x32_bf16(ql1, kh1, acc, 0, 0, 0);
#pragma unroll
        for (int g = 0; g < 4; ++g) {
            const int row = (quad << 2) + g;            // C/D: row=(lane>>4)*4+reg
            sdots[(row << 10) + ((j0 + ln) ^ ((row & 7) << 2))] = acc[g] * SCALE_;
        }
    }
    __syncthreads();

    // ---- Phase 2: per-row exact top-k + softmax (wave w owns rows 4w..4w+3)
    for (int rr = 0; rr < 4; ++rr) {
        const int r   = (w << 2) + rr;
        const int swz = (r & 7) << 2;
        float* srow = &sdots[r << 10];
        unsigned key[16];
        float    pv[16];
        unsigned kmax = 0u;
#pragma unroll
        for (int m = 0; m < 16; ++m) {
            unsigned u = f2key(srow[(l + (m << 6)) ^ swz]);
            key[m] = u;
            if (u > kmax) kmax = u;
        }
#pragma unroll
        for (int off = 32; off; off >>= 1) {
            unsigned o = __shfl_xor(kmax, off, 64);
            if (o > kmax) kmax = o;
        }
        unsigned res = 0u;
        for (int bit = 31; bit >= 0; --bit) {
            unsigned trial = res | (1u << bit);
            int c = 0;
#pragma unroll
            for (int m = 0; m < 16; ++m) c += (key[m] >= trial) ? 1 : 0;
#pragma unroll
            for (int off = 32; off; off >>= 1) c += __shfl_xor(c, off, 64);
            if (c >= KK_) res = trial;   // wave-uniform
        }
        const float mx = key2f(kmax);
        float lsum = 0.f;
#pragma unroll
        for (int m = 0; m < 16; ++m) {
            float p = (key[m] >= res) ? __expf(key2f(key[m]) - mx) : 0.f;
            pv[m] = p;
            lsum += p;
        }
#pragma unroll
        for (int off = 32; off; off >>= 1) lsum += __shfl_xor(lsum, off, 64);
        const float inv = 1.f / lsum;
#pragma unroll
        for (int m = 0; m < 16; ++m) srow[(l + (m << 6)) ^ swz] = pv[m] * inv;
    }
    __syncthreads();

    // ---- Phase 3: O = P @ V. wave w owns d-block [16w, 16w+16).
    f32x4 oacc = {0.f, 0.f, 0.f, 0.f};
    const unsigned short* vp =
        Vt + ((size_t)bh << 16) + (size_t)((w << 4) + ln) * 1024 + (quad << 3);
    const int swA = (ln & 7) << 2;
    const float* pr = &sdots[ln << 10];
    for (int j0 = 0; j0 < 1024; j0 += 32) {
        const int ja = j0 + (quad << 3);
        f32x4 p0 = *(const f32x4*)&pr[ja ^ swA];
        f32x4 p1 = *(const f32x4*)&pr[(ja + 4) ^ swA];
        bf16x8 af;
        af[0] = (short)bf16_rne(p0[0]);
        af[1] = (short)bf16_rne(p0[1]);
        af[2] = (short)bf16_rne(p0[2]);
        af[3] = (short)bf16_rne(p0[3]);
        af[4] = (short)bf16_rne(p1[0]);
        af[5] = (short)bf16_rne(p1[1]);
        af[6] = (short)bf16_rne(p1[2]);
        af[7] = (short)bf16_rne(p1[3]);
        bf16x8 bv = *(const bf16x8*)(vp + j0);
        oacc = __builtin_amdgcn_mfma_f32_16x16x32_bf16(af, bv, oacc, 0, 0, 0);
    }
    const int b = bh >> 3, h = bh & 7;
    float* ob = attn_out + ((size_t)(b << 10) + i0) * 512 + (h << 6) + (w << 4) + ln;
#pragma unroll
    for (int g = 0; g < 4; ++g)
        ob[(size_t)((quad << 2) + g) * 512] = oacc[g];
}

extern "C" void kernel_launch(void* const* d_in, const int* in_sizes, int n_in,
                              void* d_out, int out_size, void* d_ws, size_t ws_size,
                              hipStream_t stream) {
    const float* x     = (const float*)d_in[0];
    const float* w_qkv = (const float*)d_in[1];
    const float* w_out = (const float*)d_in[2];
    const float* b_out = (const float*)d_in[3];
    float*       out   = (float*)d_out;

    const size_t QK = (size_t)32 * 1024 * 64;          // 2,097,152 elems (4 MB bf16)
    unsigned short* Qh = (unsigned short*)d_ws;
    unsigned short* Ql = Qh + QK;
    unsigned short* Kh = Ql + QK;
    unsigned short* Kl = Kh + QK;
    unsigned short* Vt = Kl + QK;                      // [bh][d][n]
    float* attn_out = (float*)(Vt + QK);               // 8.4 MB fp32

    gemm_qkv<<<dim3(TRIPLE_ / 64, (B_ * N_) / 64), 256, 0, stream>>>(
        x, w_qkv, Qh, Ql, Kh, Kl, Vt);

    attn_mfma<<<dim3(B_ * H_ * (N_ / 16)), 256, 0, stream>>>(
        Qh, Ql, Kh, Kl, Vt, attn_out);

    gemm_f32<B_ * N_, DIM_, INNER_, true>
        <<<dim3(DIM_ / 64, (B_ * N_) / 64), 256, 0, stream>>>(attn_out, w_out, b_out, out);
}

// Round 3
// 332.020 us; speedup vs baseline: 5.9169x; 1.3289x over previous
//
#include <hip/hip_runtime.h>
#include <cstddef>

#define B_      4
#define N_      1024
#define DIM_    512
#define H_      8
#define D_      64
#define INNER_  512
#define TRIPLE_ 1536
#define KK_     716        // int(1024 * 0.7)
#define SCALE_  0.125f     // 64^-0.5

typedef short bf16x8 __attribute__((ext_vector_type(8)));
typedef float f32x4  __attribute__((ext_vector_type(4)));
typedef unsigned short ushort_t;

__device__ __forceinline__ unsigned short bf16_rne(float f) {
    unsigned u = __float_as_uint(f);
    return (unsigned short)((u + 0x7FFFu + ((u >> 16) & 1u)) >> 16);
}
__device__ __forceinline__ float bf16_f(unsigned short s) {
    return __uint_as_float((unsigned)s << 16);
}
// order-preserving float->uint key (descending float == descending uint)
__device__ __forceinline__ unsigned f2key(float f) {
    unsigned u = __float_as_uint(f);
    return u ^ ((u & 0x80000000u) ? 0xFFFFFFFFu : 0x80000000u);
}
__device__ __forceinline__ float key2f(unsigned k) {
    unsigned u = (k & 0x80000000u) ? (k ^ 0x80000000u) : ~k;
    return __uint_as_float(u);
}

// ---------------------------------------------------------------------------
// f32 -> hi/lo bf16 elementwise split (4 elems/thread)
// ---------------------------------------------------------------------------
__global__ __launch_bounds__(256) void conv_split(const float* __restrict__ in,
                                                  ushort_t* __restrict__ h,
                                                  ushort_t* __restrict__ l, int n4) {
    int i = blockIdx.x * 256 + threadIdx.x;
    if (i >= n4) return;
    float4 v = ((const float4*)in)[i];
    float vv[4] = {v.x, v.y, v.z, v.w};
    ushort_t hv[4], lv[4];
#pragma unroll
    for (int j = 0; j < 4; ++j) {
        hv[j] = bf16_rne(vv[j]);
        lv[j] = bf16_rne(vv[j] - bf16_f(hv[j]));
    }
    ((ushort4*)h)[i] = make_ushort4(hv[0], hv[1], hv[2], hv[3]);
    ((ushort4*)l)[i] = make_ushort4(lv[0], lv[1], lv[2], lv[3]);
}

// ---------------------------------------------------------------------------
// W[K][Nn] f32  ->  Th[Nn][K], Tl[Nn][K] bf16 (transpose + split), 32x32 tiles
// ---------------------------------------------------------------------------
__global__ __launch_bounds__(256) void conv_wT(const float* __restrict__ W,
                                               ushort_t* __restrict__ Th,
                                               ushort_t* __restrict__ Tl,
                                               int K, int Nn) {
    __shared__ float tile[32][33];
    const int nb = blockIdx.x * 32, kb = blockIdx.y * 32;
    const int tx = threadIdx.x & 31, ty = threadIdx.x >> 5;   // ty 0..7
    for (int yy = ty; yy < 32; yy += 8)
        tile[yy][tx] = W[(size_t)(kb + yy) * Nn + nb + tx];
    __syncthreads();
    for (int yy = ty; yy < 32; yy += 8) {
        float v = tile[tx][yy];
        ushort_t hb = bf16_rne(v);
        size_t idx = (size_t)(nb + yy) * K + kb + tx;
        Th[idx] = hb;
        Tl[idx] = bf16_rne(v - bf16_f(hb));
    }
}

// ---------------------------------------------------------------------------
// Split-bf16 MFMA GEMM core: wave = 32 rows x 64 cols, WG = 4 waves = 128 rows.
// A: Ah/Al [M][K] bf16 (k-contig); B: Bh/Bl [N][K] bf16 (transposed, k-contig).
// 3 products (ah*bh + al*bh + ah*bl) ~= fp32.
// ---------------------------------------------------------------------------
#define GEMM_CORE(K_DIM, AH, AL, BH, BL)                                     \
    const int t = threadIdx.x, w = t >> 6, l = t & 63;                       \
    const int ln = l & 15, quad = l >> 4;                                    \
    const int n0 = blockIdx.x * 64;                                          \
    const int m0 = blockIdx.y * 128 + w * 32;                                \
    f32x4 acc[2][4] = {};                                                    \
    {                                                                        \
        const size_t arow0 = (size_t)(m0 + ln) * (K_DIM);                    \
        const size_t arow1 = (size_t)(m0 + 16 + ln) * (K_DIM);               \
        for (int k0 = 0; k0 < (K_DIM); k0 += 32) {                           \
            const int ko = k0 + quad * 8;                                    \
            bf16x8 ah0 = *(const bf16x8*)&AH[arow0 + ko];                    \
            bf16x8 al0 = *(const bf16x8*)&AL[arow0 + ko];                    \
            bf16x8 ah1 = *(const bf16x8*)&AH[arow1 + ko];                    \
            bf16x8 al1 = *(const bf16x8*)&AL[arow1 + ko];                    \
            _Pragma("unroll")                                                \
            for (int j = 0; j < 4; ++j) {                                    \
                const size_t brow = (size_t)(n0 + j * 16 + ln) * (K_DIM) + ko; \
                bf16x8 bh = *(const bf16x8*)&BH[brow];                       \
                bf16x8 bl = *(const bf16x8*)&BL[brow];                       \
                acc[0][j] = __builtin_amdgcn_mfma_f32_16x16x32_bf16(ah0, bh, acc[0][j], 0, 0, 0); \
                acc[0][j] = __builtin_amdgcn_mfma_f32_16x16x32_bf16(al0, bh, acc[0][j], 0, 0, 0); \
                acc[0][j] = __builtin_amdgcn_mfma_f32_16x16x32_bf16(ah0, bl, acc[0][j], 0, 0, 0); \
                acc[1][j] = __builtin_amdgcn_mfma_f32_16x16x32_bf16(ah1, bh, acc[1][j], 0, 0, 0); \
                acc[1][j] = __builtin_amdgcn_mfma_f32_16x16x32_bf16(al1, bh, acc[1][j], 0, 0, 0); \
                acc[1][j] = __builtin_amdgcn_mfma_f32_16x16x32_bf16(ah1, bl, acc[1][j], 0, 0, 0); \
            }                                                                \
        }                                                                    \
    }

// qkv: C cols 0..511 = Q, 512..1023 = K, 1024..1535 = V; per-head d = col&63.
__global__ __launch_bounds__(256) void gemm_qkv_mfma(
    const ushort_t* __restrict__ Xh, const ushort_t* __restrict__ Xl,
    const ushort_t* __restrict__ Wh, const ushort_t* __restrict__ Wl,
    ushort_t* __restrict__ Qh, ushort_t* __restrict__ Ql,
    ushort_t* __restrict__ Kh, ushort_t* __restrict__ Kl,
    ushort_t* __restrict__ Vt) {
    GEMM_CORE(DIM_, Xh, Xl, Wh, Wl)
    const int sec = n0 >> 9;
    const int h   = (n0 >> 6) & 7;
#pragma unroll
    for (int i = 0; i < 2; ++i)
#pragma unroll
        for (int j = 0; j < 4; ++j)
#pragma unroll
            for (int g = 0; g < 4; ++g) {
                const int token = m0 + i * 16 + quad * 4 + g;
                const int d = j * 16 + ln;
                const int b = token >> 10, nn = token & 1023;
                const float v = acc[i][j][g];
                if (sec < 2) {
                    size_t base = ((size_t)(b * 8 + h) * 1024 + nn) * 64 + d;
                    ushort_t hb = bf16_rne(v);
                    ushort_t lb = bf16_rne(v - bf16_f(hb));
                    if (sec == 0) { Qh[base] = hb; Ql[base] = lb; }
                    else          { Kh[base] = hb; Kl[base] = lb; }
                } else {
                    Vt[((size_t)(b * 8 + h) * 64 + d) * 1024 + nn] = bf16_rne(v);
                }
            }
}

// out-proj: fp32 C + bias
__global__ __launch_bounds__(256) void gemm_out_mfma(
    const ushort_t* __restrict__ Ah, const ushort_t* __restrict__ Al,
    const ushort_t* __restrict__ Wh, const ushort_t* __restrict__ Wl,
    const float* __restrict__ bias, float* __restrict__ C) {
    GEMM_CORE(INNER_, Ah, Al, Wh, Wl)
#pragma unroll
    for (int i = 0; i < 2; ++i)
#pragma unroll
        for (int j = 0; j < 4; ++j) {
            const int col = n0 + j * 16 + ln;
            const float bb = bias[col];
#pragma unroll
            for (int g = 0; g < 4; ++g) {
                const int token = m0 + i * 16 + quad * 4 + g;
                C[(size_t)token * DIM_ + col] = acc[i][j][g] + bb;
            }
        }
}

// ---------------------------------------------------------------------------
// MFMA kNN attention. WG = 256 thr (4 waves) = (b,h, 16 q-rows).
// Phase 1: split-bf16 QK^T -> fp32 LDS (swizzled).
// Phase 2: exact top-k via ballot-count binary search (early exit), softmax,
//          normalized P stored bf16 IN PLACE (first 2KB of each row slot).
// Phase 3: P @ V via MFMA; A-frags = ds_read_b128 of bf16 P, B = Vt global.
// Epilogue: O written hi/lo bf16 for the out-proj.
// ---------------------------------------------------------------------------
__global__ __launch_bounds__(256) void attn_mfma(const ushort_t* __restrict__ Qh,
                                                 const ushort_t* __restrict__ Ql,
                                                 const ushort_t* __restrict__ Kh,
                                                 const ushort_t* __restrict__ Kl,
                                                 const ushort_t* __restrict__ Vt,
                                                 ushort_t* __restrict__ Oh,
                                                 ushort_t* __restrict__ Ol) {
    __shared__ float sdots[16 * 1024];   // exactly 64 KB

    const int t    = threadIdx.x;
    const int w    = t >> 6;
    const int l    = t & 63;
    const int ln   = l & 15;
    const int quad = l >> 4;
    const int wg   = blockIdx.x;
    const int bh   = wg >> 6;
    const int i0   = (wg & 63) << 4;

    const size_t bhoff = (size_t)bh << 16;

    // ---- Q fragments
    const ushort_t* qp  = Qh + bhoff + (size_t)(i0 + ln) * 64 + (quad << 3);
    const ushort_t* qlp = Ql + bhoff + (size_t)(i0 + ln) * 64 + (quad << 3);
    bf16x8 qh0 = *(const bf16x8*)qp;
    bf16x8 qh1 = *(const bf16x8*)(qp + 32);
    bf16x8 ql0 = *(const bf16x8*)qlp;
    bf16x8 ql1 = *(const bf16x8*)(qlp + 32);

    // ---- Phase 1: dots
    for (int tt = 0; tt < 16; ++tt) {
        const int j0 = ((w << 4) + tt) << 4;
        const ushort_t* kp  = Kh + bhoff + (size_t)(j0 + ln) * 64 + (quad << 3);
        const ushort_t* klp = Kl + bhoff + (size_t)(j0 + ln) * 64 + (quad << 3);
        bf16x8 kh0 = *(const bf16x8*)kp;
        bf16x8 kh1 = *(const bf16x8*)(kp + 32);
        bf16x8 kl0 = *(const bf16x8*)klp;
        bf16x8 kl1 = *(const bf16x8*)(klp + 32);
        f32x4 acc = {0.f, 0.f, 0.f, 0.f};
        acc = __builtin_amdgcn_mfma_f32_16x16x32_bf16(qh0, kh0, acc, 0, 0, 0);
        acc = __builtin_amdgcn_mfma_f32_16x16x32_bf16(qh1, kh1, acc, 0, 0, 0);
        acc = __builtin_amdgcn_mfma_f32_16x16x32_bf16(qh0, kl0, acc, 0, 0, 0);
        acc = __builtin_amdgcn_mfma_f32_16x16x32_bf16(qh1, kl1, acc, 0, 0, 0);
        acc = __builtin_amdgcn_mfma_f32_16x16x32_bf16(ql0, kh0, acc, 0, 0, 0);
        acc = __builtin_amdgcn_mfma_f32_16x16x32_bf16(ql1, kh1, acc, 0, 0, 0);
#pragma unroll
        for (int g = 0; g < 4; ++g) {
            const int row = (quad << 2) + g;
            sdots[(row << 10) + ((j0 + ln) ^ ((row & 7) << 2))] = acc[g] * SCALE_;
        }
    }
    __syncthreads();

    // ---- Phase 2: top-k (ballot count) + softmax + in-place bf16 P
    ushort_t* sP = (ushort_t*)sdots;
    for (int rr = 0; rr < 4; ++rr) {
        const int r   = (w << 2) + rr;
        const int swz = (r & 7) << 2;
        const float* srow = &sdots[r << 10];
        unsigned key[16];
        float    pv[16];
        unsigned kmax = 0u;
#pragma unroll
        for (int m = 0; m < 16; ++m) {
            unsigned u = f2key(srow[(l + (m << 6)) ^ swz]);
            key[m] = u;
            if (u > kmax) kmax = u;
        }
#pragma unroll
        for (int off = 32; off; off >>= 1) {
            unsigned o = __shfl_xor(kmax, off, 64);
            if (o > kmax) kmax = o;
        }
        unsigned res = 0u;
        for (int bit = 31; bit >= 0; --bit) {
            unsigned trial = res | (1u << bit);
            int c = 0;
#pragma unroll
            for (int m = 0; m < 16; ++m)
                c += __popcll(__ballot(key[m] >= trial));
            if (c >= KK_) {
                res = trial;
                if (c == KK_) break;   // wave-uniform
            }
        }
        const float mx = key2f(kmax);
        float lsum = 0.f;
#pragma unroll
        for (int m = 0; m < 16; ++m) {
            float p = (key[m] >= res) ? __expf(key2f(key[m]) - mx) : 0.f;
            pv[m] = p;
            lsum += p;
        }
#pragma unroll
        for (int off = 32; off; off >>= 1) lsum += __shfl_xor(lsum, off, 64);
        const float inv = 1.f / lsum;
#pragma unroll
        for (int m = 0; m < 16; ++m) {
            const int j = l + (m << 6);
            const int g = (j >> 3) ^ (r & 7);
            sP[(r << 11) + (g << 3) + (j & 7)] = bf16_rne(pv[m] * inv);
        }
    }
    __syncthreads();

    // ---- Phase 3: O = P @ V
    f32x4 oacc = {0.f, 0.f, 0.f, 0.f};
    const ushort_t* vp = Vt + bhoff + (size_t)((w << 4) + ln) * 1024 + (quad << 3);
    const int prow = ln << 11;
    const int rsw  = ln & 7;
    for (int j0 = 0; j0 < 1024; j0 += 32) {
        const int g = (j0 >> 3) + quad;
        bf16x8 af = *(const bf16x8*)&sP[prow + ((g ^ rsw) << 3)];
        bf16x8 bv = *(const bf16x8*)(vp + j0);
        oacc = __builtin_amdgcn_mfma_f32_16x16x32_bf16(af, bv, oacc, 0, 0, 0);
    }
    const int b = bh >> 3, h = bh & 7;
    const size_t obase =
        ((size_t)(b << 10) + i0 + (quad << 2)) * 512 + (h << 6) + (w << 4) + ln;
#pragma unroll
    for (int g = 0; g < 4; ++g) {
        const float v = oacc[g];
        ushort_t hb = bf16_rne(v);
        Oh[obase + (size_t)g * 512] = hb;
        Ol[obase + (size_t)g * 512] = bf16_rne(v - bf16_f(hb));
    }
}

extern "C" void kernel_launch(void* const* d_in, const int* in_sizes, int n_in,
                              void* d_out, int out_size, void* d_ws, size_t ws_size,
                              hipStream_t stream) {
    const float* x     = (const float*)d_in[0];
    const float* w_qkv = (const float*)d_in[1];
    const float* w_out = (const float*)d_in[2];
    const float* b_out = (const float*)d_in[3];
    float*       out   = (float*)d_out;

    const size_t XN  = (size_t)4096 * 512;   // 2,097,152
    const size_t WQT = (size_t)1536 * 512;   //   786,432
    const size_t WOT = (size_t)512 * 512;    //   262,144
    const size_t QK  = (size_t)32 * 1024 * 64;

    ushort_t* p    = (ushort_t*)d_ws;
    ushort_t* Xh   = p;            p += XN;
    ushort_t* Xl   = p;            p += XN;
    ushort_t* WqTh = p;            p += WQT;
    ushort_t* WqTl = p;            p += WQT;
    ushort_t* WoTh = p;            p += WOT;
    ushort_t* WoTl = p;            p += WOT;
    ushort_t* Qh   = p;            p += QK;
    ushort_t* Ql   = p;            p += QK;
    ushort_t* Kh   = p;            p += QK;
    ushort_t* Kl   = p;            p += QK;
    ushort_t* Vt   = p;            p += QK;
    // O aliases X (x is dead after gemm_qkv_mfma) — total exactly 32 MiB
    ushort_t* Oh = Xh;
    ushort_t* Ol = Xl;

    conv_split<<<dim3((XN / 4 + 255) / 256), 256, 0, stream>>>(x, Xh, Xl, (int)(XN / 4));
    conv_wT<<<dim3(TRIPLE_ / 32, DIM_ / 32), 256, 0, stream>>>(w_qkv, WqTh, WqTl, DIM_, TRIPLE_);
    conv_wT<<<dim3(DIM_ / 32, INNER_ / 32), 256, 0, stream>>>(w_out, WoTh, WoTl, INNER_, DIM_);

    gemm_qkv_mfma<<<dim3(TRIPLE_ / 64, 4096 / 128), 256, 0, stream>>>(
        Xh, Xl, WqTh, WqTl, Qh, Ql, Kh, Kl, Vt);

    attn_mfma<<<dim3(B_ * H_ * (N_ / 16)), 256, 0, stream>>>(Qh, Ql, Kh, Kl, Vt, Oh, Ol);

    gemm_out_mfma<<<dim3(DIM_ / 64, 4096 / 128), 256, 0, stream>>>(
        Oh, Ol, WoTh, WoTl, b_out, out);
}

// Round 4
// 328.412 us; speedup vs baseline: 5.9819x; 1.0110x over previous
//
#include <hip/hip_runtime.h>
#include <cstddef>

#define B_      4
#define N_      1024
#define DIM_    512
#define H_      8
#define D_      64
#define INNER_  512
#define TRIPLE_ 1536
#define KK_     716        // int(1024 * 0.7)
#define SCALE_  0.125f     // 64^-0.5

typedef short bf16x8 __attribute__((ext_vector_type(8)));
typedef float f32x4  __attribute__((ext_vector_type(4)));
typedef unsigned short ushort_t;

__device__ __forceinline__ unsigned short bf16_rne(float f) {
    unsigned u = __float_as_uint(f);
    return (unsigned short)((u + 0x7FFFu + ((u >> 16) & 1u)) >> 16);
}
__device__ __forceinline__ float bf16_f(unsigned short s) {
    return __uint_as_float((unsigned)s << 16);
}
// order-preserving float->uint key (descending float == descending uint)
__device__ __forceinline__ unsigned f2key(float f) {
    unsigned u = __float_as_uint(f);
    return u ^ ((u & 0x80000000u) ? 0xFFFFFFFFu : 0x80000000u);
}
__device__ __forceinline__ float key2f(unsigned k) {
    unsigned u = (k & 0x80000000u) ? (k ^ 0x80000000u) : ~k;
    return __uint_as_float(u);
}

// ---------------------------------------------------------------------------
// f32 -> hi/lo bf16 elementwise split (4 elems/thread)
// ---------------------------------------------------------------------------
__global__ __launch_bounds__(256) void conv_split(const float* __restrict__ in,
                                                  ushort_t* __restrict__ h,
                                                  ushort_t* __restrict__ l, int n4) {
    int i = blockIdx.x * 256 + threadIdx.x;
    if (i >= n4) return;
    float4 v = ((const float4*)in)[i];
    float vv[4] = {v.x, v.y, v.z, v.w};
    ushort_t hv[4], lv[4];
#pragma unroll
    for (int j = 0; j < 4; ++j) {
        hv[j] = bf16_rne(vv[j]);
        lv[j] = bf16_rne(vv[j] - bf16_f(hv[j]));
    }
    ((ushort4*)h)[i] = make_ushort4(hv[0], hv[1], hv[2], hv[3]);
    ((ushort4*)l)[i] = make_ushort4(lv[0], lv[1], lv[2], lv[3]);
}

// ---------------------------------------------------------------------------
// W[K][Nn] f32  ->  Th[Nn][K], Tl[Nn][K] bf16 (transpose + split), 32x32 tiles
// ---------------------------------------------------------------------------
__global__ __launch_bounds__(256) void conv_wT(const float* __restrict__ W,
                                               ushort_t* __restrict__ Th,
                                               ushort_t* __restrict__ Tl,
                                               int K, int Nn) {
    __shared__ float tile[32][33];
    const int nb = blockIdx.x * 32, kb = blockIdx.y * 32;
    const int tx = threadIdx.x & 31, ty = threadIdx.x >> 5;   // ty 0..7
    for (int yy = ty; yy < 32; yy += 8)
        tile[yy][tx] = W[(size_t)(kb + yy) * Nn + nb + tx];
    __syncthreads();
    for (int yy = ty; yy < 32; yy += 8) {
        float v = tile[tx][yy];
        ushort_t hb = bf16_rne(v);
        size_t idx = (size_t)(nb + yy) * K + kb + tx;
        Th[idx] = hb;
        Tl[idx] = bf16_rne(v - bf16_f(hb));
    }
}

// ---------------------------------------------------------------------------
// Split-bf16 MFMA GEMM core: wave = 32 rows x 64 cols, WG = 4 waves = 128 rows.
// blockIdx.x = M-block (XCD-local A tiles), blockIdx.y = N-block.
// ---------------------------------------------------------------------------
#define GEMM_CORE(K_DIM, AH, AL, BH, BL)                                     \
    const int t = threadIdx.x, w = t >> 6, l = t & 63;                       \
    const int ln = l & 15, quad = l >> 4;                                    \
    const int n0 = blockIdx.y * 64;                                          \
    const int m0 = blockIdx.x * 128 + w * 32;                                \
    f32x4 acc[2][4] = {};                                                    \
    {                                                                        \
        const size_t arow0 = (size_t)(m0 + ln) * (K_DIM);                    \
        const size_t arow1 = (size_t)(m0 + 16 + ln) * (K_DIM);               \
        for (int k0 = 0; k0 < (K_DIM); k0 += 32) {                           \
            const int ko = k0 + quad * 8;                                    \
            bf16x8 ah0 = *(const bf16x8*)&AH[arow0 + ko];                    \
            bf16x8 al0 = *(const bf16x8*)&AL[arow0 + ko];                    \
            bf16x8 ah1 = *(const bf16x8*)&AH[arow1 + ko];                    \
            bf16x8 al1 = *(const bf16x8*)&AL[arow1 + ko];                    \
            _Pragma("unroll")                                                \
            for (int j = 0; j < 4; ++j) {                                    \
                const size_t brow = (size_t)(n0 + j * 16 + ln) * (K_DIM) + ko; \
                bf16x8 bh = *(const bf16x8*)&BH[brow];                       \
                bf16x8 bl = *(const bf16x8*)&BL[brow];                       \
                acc[0][j] = __builtin_amdgcn_mfma_f32_16x16x32_bf16(ah0, bh, acc[0][j], 0, 0, 0); \
                acc[0][j] = __builtin_amdgcn_mfma_f32_16x16x32_bf16(al0, bh, acc[0][j], 0, 0, 0); \
                acc[0][j] = __builtin_amdgcn_mfma_f32_16x16x32_bf16(ah0, bl, acc[0][j], 0, 0, 0); \
                acc[1][j] = __builtin_amdgcn_mfma_f32_16x16x32_bf16(ah1, bh, acc[1][j], 0, 0, 0); \
                acc[1][j] = __builtin_amdgcn_mfma_f32_16x16x32_bf16(al1, bh, acc[1][j], 0, 0, 0); \
                acc[1][j] = __builtin_amdgcn_mfma_f32_16x16x32_bf16(ah1, bl, acc[1][j], 0, 0, 0); \
            }                                                                \
        }                                                                    \
    }

// qkv: C cols 0..511 = Q, 512..1023 = K, 1024..1535 = V; per-head d = col&63.
__global__ __launch_bounds__(256) void gemm_qkv_mfma(
    const ushort_t* __restrict__ Xh, const ushort_t* __restrict__ Xl,
    const ushort_t* __restrict__ Wh, const ushort_t* __restrict__ Wl,
    ushort_t* __restrict__ Qh, ushort_t* __restrict__ Ql,
    ushort_t* __restrict__ Kh, ushort_t* __restrict__ Kl,
    ushort_t* __restrict__ Vt) {
    GEMM_CORE(DIM_, Xh, Xl, Wh, Wl)
    const int sec = n0 >> 9;
    const int h   = (n0 >> 6) & 7;
#pragma unroll
    for (int i = 0; i < 2; ++i)
#pragma unroll
        for (int j = 0; j < 4; ++j)
#pragma unroll
            for (int g = 0; g < 4; ++g) {
                const int token = m0 + i * 16 + quad * 4 + g;
                const int d = j * 16 + ln;
                const int b = token >> 10, nn = token & 1023;
                const float v = acc[i][j][g];
                if (sec < 2) {
                    size_t base = ((size_t)(b * 8 + h) * 1024 + nn) * 64 + d;
                    ushort_t hb = bf16_rne(v);
                    ushort_t lb = bf16_rne(v - bf16_f(hb));
                    if (sec == 0) { Qh[base] = hb; Ql[base] = lb; }
                    else          { Kh[base] = hb; Kl[base] = lb; }
                } else {
                    Vt[((size_t)(b * 8 + h) * 64 + d) * 1024 + nn] = bf16_rne(v);
                }
            }
}

// out-proj: fp32 C + bias
__global__ __launch_bounds__(256) void gemm_out_mfma(
    const ushort_t* __restrict__ Ah, const ushort_t* __restrict__ Al,
    const ushort_t* __restrict__ Wh, const ushort_t* __restrict__ Wl,
    const float* __restrict__ bias, float* __restrict__ C) {
    GEMM_CORE(INNER_, Ah, Al, Wh, Wl)
#pragma unroll
    for (int i = 0; i < 2; ++i)
#pragma unroll
        for (int j = 0; j < 4; ++j) {
            const int col = n0 + j * 16 + ln;
            const float bb = bias[col];
#pragma unroll
            for (int g = 0; g < 4; ++g) {
                const int token = m0 + i * 16 + quad * 4 + g;
                C[(size_t)token * DIM_ + col] = acc[i][j][g] + bb;
            }
        }
}

// ---------------------------------------------------------------------------
// MFMA kNN attention. WG = 256 thr (4 waves) = (b,h, 16 q-rows).
// Grid is i0-major: bh = wg & 31  =>  all 64 blocks of one head land on the
// same XCD (block->XCD is round-robin, 32 % 8 == 0), so K/V stay in that
// XCD's 4 MiB L2 (per-XCD working set = 4 heads * 640 KB = 2.56 MB).
// Softmax references the top-k threshold instead of the row max (max-thr < 5,
// exp bounded) -- kills the max cross-lane reduction entirely.
// ---------------------------------------------------------------------------
__global__ __launch_bounds__(256) void attn_mfma(const ushort_t* __restrict__ Qh,
                                                 const ushort_t* __restrict__ Ql,
                                                 const ushort_t* __restrict__ Kh,
                                                 const ushort_t* __restrict__ Kl,
                                                 const ushort_t* __restrict__ Vt,
                                                 ushort_t* __restrict__ Oh,
                                                 ushort_t* __restrict__ Ol) {
    __shared__ float sdots[16 * 1024];   // exactly 64 KB

    const int t    = threadIdx.x;
    const int w    = t >> 6;
    const int l    = t & 63;
    const int ln   = l & 15;
    const int quad = l >> 4;
    const int wg   = blockIdx.x;
    const int bh   = wg & 31;            // XCD-local heads
    const int i0   = (wg >> 5) << 4;

    const size_t bhoff = (size_t)bh << 16;

    // ---- Q fragments
    const ushort_t* qp  = Qh + bhoff + (size_t)(i0 + ln) * 64 + (quad << 3);
    const ushort_t* qlp = Ql + bhoff + (size_t)(i0 + ln) * 64 + (quad << 3);
    bf16x8 qh0 = *(const bf16x8*)qp;
    bf16x8 qh1 = *(const bf16x8*)(qp + 32);
    bf16x8 ql0 = *(const bf16x8*)qlp;
    bf16x8 ql1 = *(const bf16x8*)(qlp + 32);

    // ---- Phase 1: dots
    for (int tt = 0; tt < 16; ++tt) {
        const int j0 = ((w << 4) + tt) << 4;
        const ushort_t* kp  = Kh + bhoff + (size_t)(j0 + ln) * 64 + (quad << 3);
        const ushort_t* klp = Kl + bhoff + (size_t)(j0 + ln) * 64 + (quad << 3);
        bf16x8 kh0 = *(const bf16x8*)kp;
        bf16x8 kh1 = *(const bf16x8*)(kp + 32);
        bf16x8 kl0 = *(const bf16x8*)klp;
        bf16x8 kl1 = *(const bf16x8*)(klp + 32);
        f32x4 acc = {0.f, 0.f, 0.f, 0.f};
        acc = __builtin_amdgcn_mfma_f32_16x16x32_bf16(qh0, kh0, acc, 0, 0, 0);
        acc = __builtin_amdgcn_mfma_f32_16x16x32_bf16(qh1, kh1, acc, 0, 0, 0);
        acc = __builtin_amdgcn_mfma_f32_16x16x32_bf16(qh0, kl0, acc, 0, 0, 0);
        acc = __builtin_amdgcn_mfma_f32_16x16x32_bf16(qh1, kl1, acc, 0, 0, 0);
        acc = __builtin_amdgcn_mfma_f32_16x16x32_bf16(ql0, kh0, acc, 0, 0, 0);
        acc = __builtin_amdgcn_mfma_f32_16x16x32_bf16(ql1, kh1, acc, 0, 0, 0);
#pragma unroll
        for (int g = 0; g < 4; ++g) {
            const int row = (quad << 2) + g;
            sdots[(row << 10) + ((j0 + ln) ^ ((row & 7) << 2))] = acc[g] * SCALE_;
        }
    }
    __syncthreads();

    // ---- Phase 2: top-k (ballot count) + softmax(ref=thr) + in-place bf16 P
    ushort_t* sP = (ushort_t*)sdots;
    for (int rr = 0; rr < 4; ++rr) {
        const int r   = (w << 2) + rr;
        const int swz = (r & 7) << 2;
        const float* srow = &sdots[r << 10];
        unsigned key[16];
        float    pv[16];
#pragma unroll
        for (int m = 0; m < 16; ++m)
            key[m] = f2key(srow[(l + (m << 6)) ^ swz]);
        unsigned res = 0u;
        for (int bit = 31; bit >= 0; --bit) {
            unsigned trial = res | (1u << bit);
            int c = 0;
#pragma unroll
            for (int m = 0; m < 16; ++m)
                c += __popcll(__ballot(key[m] >= trial));
            if (c >= KK_) {
                res = trial;
                if (c == KK_) break;   // wave-uniform
            }
        }
        const float thr = key2f(res);
        float lsum = 0.f;
#pragma unroll
        for (int m = 0; m < 16; ++m) {
            float p = (key[m] >= res) ? __expf(key2f(key[m]) - thr) : 0.f;
            pv[m] = p;
            lsum += p;
        }
#pragma unroll
        for (int off = 32; off; off >>= 1) lsum += __shfl_xor(lsum, off, 64);
        const float inv = 1.f / lsum;
#pragma unroll
        for (int m = 0; m < 16; ++m) {
            const int j = l + (m << 6);
            const int g = (j >> 3) ^ (r & 7);
            sP[(r << 11) + (g << 3) + (j & 7)] = bf16_rne(pv[m] * inv);
        }
    }
    __syncthreads();

    // ---- Phase 3: O = P @ V
    f32x4 oacc = {0.f, 0.f, 0.f, 0.f};
    const ushort_t* vp = Vt + bhoff + (size_t)((w << 4) + ln) * 1024 + (quad << 3);
    const int prow = ln << 11;
    const int rsw  = ln & 7;
    for (int j0 = 0; j0 < 1024; j0 += 32) {
        const int g = (j0 >> 3) + quad;
        bf16x8 af = *(const bf16x8*)&sP[prow + ((g ^ rsw) << 3)];
        bf16x8 bv = *(const bf16x8*)(vp + j0);
        oacc = __builtin_amdgcn_mfma_f32_16x16x32_bf16(af, bv, oacc, 0, 0, 0);
    }
    const int b = bh >> 3, h = bh & 7;
    const size_t obase =
        ((size_t)(b << 10) + i0 + (quad << 2)) * 512 + (h << 6) + (w << 4) + ln;
#pragma unroll
    for (int g = 0; g < 4; ++g) {
        const float v = oacc[g];
        ushort_t hb = bf16_rne(v);
        Oh[obase + (size_t)g * 512] = hb;
        Ol[obase + (size_t)g * 512] = bf16_rne(v - bf16_f(hb));
    }
}

extern "C" void kernel_launch(void* const* d_in, const int* in_sizes, int n_in,
                              void* d_out, int out_size, void* d_ws, size_t ws_size,
                              hipStream_t stream) {
    const float* x     = (const float*)d_in[0];
    const float* w_qkv = (const float*)d_in[1];
    const float* w_out = (const float*)d_in[2];
    const float* b_out = (const float*)d_in[3];
    float*       out   = (float*)d_out;

    const size_t XN  = (size_t)4096 * 512;
    const size_t WQT = (size_t)1536 * 512;
    const size_t WOT = (size_t)512 * 512;
    const size_t QK  = (size_t)32 * 1024 * 64;

    ushort_t* p    = (ushort_t*)d_ws;
    ushort_t* Xh   = p;            p += XN;
    ushort_t* Xl   = p;            p += XN;
    ushort_t* WqTh = p;            p += WQT;
    ushort_t* WqTl = p;            p += WQT;
    ushort_t* WoTh = p;            p += WOT;
    ushort_t* WoTl = p;            p += WOT;
    ushort_t* Qh   = p;            p += QK;
    ushort_t* Ql   = p;            p += QK;
    ushort_t* Kh   = p;            p += QK;
    ushort_t* Kl   = p;            p += QK;
    ushort_t* Vt   = p;            p += QK;
    // O aliases X (x is dead after gemm_qkv_mfma) — total exactly 32 MiB
    ushort_t* Oh = Xh;
    ushort_t* Ol = Xl;

    conv_split<<<dim3((XN / 4 + 255) / 256), 256, 0, stream>>>(x, Xh, Xl, (int)(XN / 4));
    conv_wT<<<dim3(TRIPLE_ / 32, DIM_ / 32), 256, 0, stream>>>(w_qkv, WqTh, WqTl, DIM_, TRIPLE_);
    conv_wT<<<dim3(DIM_ / 32, INNER_ / 32), 256, 0, stream>>>(w_out, WoTh, WoTl, INNER_, DIM_);

    // blockIdx.x = m-block so A tiles are XCD-local
    gemm_qkv_mfma<<<dim3(4096 / 128, TRIPLE_ / 64), 256, 0, stream>>>(
        Xh, Xl, WqTh, WqTl, Qh, Ql, Kh, Kl, Vt);

    attn_mfma<<<dim3(B_ * H_ * (N_ / 16)), 256, 0, stream>>>(Qh, Ql, Kh, Kl, Vt, Oh, Ol);

    gemm_out_mfma<<<dim3(4096 / 128, DIM_ / 64), 256, 0, stream>>>(
        Oh, Ol, WoTh, WoTl, b_out, out);
}

// Round 5
// 316.521 us; speedup vs baseline: 6.2067x; 1.0376x over previous
//
#include <hip/hip_runtime.h>
#include <cstddef>

#define B_      4
#define N_      1024
#define DIM_    512
#define H_      8
#define D_      64
#define INNER_  512
#define TRIPLE_ 1536
#define KK_     716        // int(1024 * 0.7)
#define SCALE_  0.125f     // 64^-0.5

typedef short bf16x8 __attribute__((ext_vector_type(8)));
typedef float f32x4  __attribute__((ext_vector_type(4)));
typedef unsigned short ushort_t;
typedef ushort_t us8 __attribute__((ext_vector_type(8)));

__device__ __forceinline__ unsigned short bf16_rne(float f) {
    unsigned u = __float_as_uint(f);
    return (unsigned short)((u + 0x7FFFu + ((u >> 16) & 1u)) >> 16);
}
__device__ __forceinline__ float bf16_f(unsigned short s) {
    return __uint_as_float((unsigned)s << 16);
}
// order-preserving float->uint key (descending float == descending uint)
__device__ __forceinline__ unsigned f2key(float f) {
    unsigned u = __float_as_uint(f);
    return u ^ ((u & 0x80000000u) ? 0xFFFFFFFFu : 0x80000000u);
}
__device__ __forceinline__ float key2f(unsigned k) {
    unsigned u = (k & 0x80000000u) ? (k ^ 0x80000000u) : ~k;
    return __uint_as_float(u);
}

// ---------------------------------------------------------------------------
// f32 -> hi/lo bf16 elementwise split (4 elems/thread)
// ---------------------------------------------------------------------------
__global__ __launch_bounds__(256) void conv_split(const float* __restrict__ in,
                                                  ushort_t* __restrict__ h,
                                                  ushort_t* __restrict__ l, int n4) {
    int i = blockIdx.x * 256 + threadIdx.x;
    if (i >= n4) return;
    float4 v = ((const float4*)in)[i];
    float vv[4] = {v.x, v.y, v.z, v.w};
    ushort_t hv[4], lv[4];
#pragma unroll
    for (int j = 0; j < 4; ++j) {
        hv[j] = bf16_rne(vv[j]);
        lv[j] = bf16_rne(vv[j] - bf16_f(hv[j]));
    }
    ((ushort4*)h)[i] = make_ushort4(hv[0], hv[1], hv[2], hv[3]);
    ((ushort4*)l)[i] = make_ushort4(lv[0], lv[1], lv[2], lv[3]);
}

// ---------------------------------------------------------------------------
// W[K][Nn] f32  ->  Th[Nn][K], Tl[Nn][K] bf16 (transpose + split), 32x32 tiles
// ---------------------------------------------------------------------------
__global__ __launch_bounds__(256) void conv_wT(const float* __restrict__ W,
                                               ushort_t* __restrict__ Th,
                                               ushort_t* __restrict__ Tl,
                                               int K, int Nn) {
    __shared__ float tile[32][33];
    const int nb = blockIdx.x * 32, kb = blockIdx.y * 32;
    const int tx = threadIdx.x & 31, ty = threadIdx.x >> 5;   // ty 0..7
    for (int yy = ty; yy < 32; yy += 8)
        tile[yy][tx] = W[(size_t)(kb + yy) * Nn + nb + tx];
    __syncthreads();
    for (int yy = ty; yy < 32; yy += 8) {
        float v = tile[tx][yy];
        ushort_t hb = bf16_rne(v);
        size_t idx = (size_t)(nb + yy) * K + kb + tx;
        Th[idx] = hb;
        Tl[idx] = bf16_rne(v - bf16_f(hb));
    }
}

// ---------------------------------------------------------------------------
// Split-bf16 MFMA GEMM core: wave = 32 rows x 64 cols, WG = 4 waves = 128 rows.
// blockIdx.x = M-block (XCD-local A tiles), blockIdx.y = N-block.
// ---------------------------------------------------------------------------
#define GEMM_CORE(K_DIM, AH, AL, BH, BL)                                     \
    const int t = threadIdx.x, w = t >> 6, l = t & 63;                       \
    const int ln = l & 15, quad = l >> 4;                                    \
    const int n0 = blockIdx.y * 64;                                          \
    const int m0 = blockIdx.x * 128 + w * 32;                                \
    f32x4 acc[2][4] = {};                                                    \
    {                                                                        \
        const size_t arow0 = (size_t)(m0 + ln) * (K_DIM);                    \
        const size_t arow1 = (size_t)(m0 + 16 + ln) * (K_DIM);               \
        for (int k0 = 0; k0 < (K_DIM); k0 += 32) {                           \
            const int ko = k0 + quad * 8;                                    \
            bf16x8 ah0 = *(const bf16x8*)&AH[arow0 + ko];                    \
            bf16x8 al0 = *(const bf16x8*)&AL[arow0 + ko];                    \
            bf16x8 ah1 = *(const bf16x8*)&AH[arow1 + ko];                    \
            bf16x8 al1 = *(const bf16x8*)&AL[arow1 + ko];                    \
            _Pragma("unroll")                                                \
            for (int j = 0; j < 4; ++j) {                                    \
                const size_t brow = (size_t)(n0 + j * 16 + ln) * (K_DIM) + ko; \
                bf16x8 bh = *(const bf16x8*)&BH[brow];                       \
                bf16x8 bl = *(const bf16x8*)&BL[brow];                       \
                acc[0][j] = __builtin_amdgcn_mfma_f32_16x16x32_bf16(ah0, bh, acc[0][j], 0, 0, 0); \
                acc[0][j] = __builtin_amdgcn_mfma_f32_16x16x32_bf16(al0, bh, acc[0][j], 0, 0, 0); \
                acc[0][j] = __builtin_amdgcn_mfma_f32_16x16x32_bf16(ah0, bl, acc[0][j], 0, 0, 0); \
                acc[1][j] = __builtin_amdgcn_mfma_f32_16x16x32_bf16(ah1, bh, acc[1][j], 0, 0, 0); \
                acc[1][j] = __builtin_amdgcn_mfma_f32_16x16x32_bf16(al1, bh, acc[1][j], 0, 0, 0); \
                acc[1][j] = __builtin_amdgcn_mfma_f32_16x16x32_bf16(ah1, bl, acc[1][j], 0, 0, 0); \
            }                                                                \
        }                                                                    \
    }

// qkv: C cols 0..511 = Q, 512..1023 = K, 1024..1535 = V; per-head d = col&63.
// V blocks transpose through LDS so Vt writes are full 64B lines.
__global__ __launch_bounds__(256) void gemm_qkv_mfma(
    const ushort_t* __restrict__ Xh, const ushort_t* __restrict__ Xl,
    const ushort_t* __restrict__ Wh, const ushort_t* __restrict__ Wl,
    ushort_t* __restrict__ Qh, ushort_t* __restrict__ Ql,
    ushort_t* __restrict__ Kh, ushort_t* __restrict__ Kl,
    ushort_t* __restrict__ Vt) {
    __shared__ ushort_t vtile[4][64][40];   // 20 KB; row stride 80B (16B-mult)
    GEMM_CORE(DIM_, Xh, Xl, Wh, Wl)
    const int sec = n0 >> 9;
    const int h   = (n0 >> 6) & 7;
    if (sec < 2) {
#pragma unroll
        for (int i = 0; i < 2; ++i)
#pragma unroll
            for (int j = 0; j < 4; ++j)
#pragma unroll
                for (int g = 0; g < 4; ++g) {
                    const int token = m0 + i * 16 + quad * 4 + g;
                    const int d = j * 16 + ln;
                    const int b = token >> 10, nn = token & 1023;
                    const float v = acc[i][j][g];
                    size_t base = ((size_t)(b * 8 + h) * 1024 + nn) * 64 + d;
                    ushort_t hb = bf16_rne(v);
                    ushort_t lb = bf16_rne(v - bf16_f(hb));
                    if (sec == 0) { Qh[base] = hb; Ql[base] = lb; }
                    else          { Kh[base] = hb; Kl[base] = lb; }
                }
    } else {
#pragma unroll
        for (int i = 0; i < 2; ++i)
#pragma unroll
            for (int j = 0; j < 4; ++j)
#pragma unroll
                for (int g = 0; g < 4; ++g)
                    vtile[w][j * 16 + ln][i * 16 + quad * 4 + g] = bf16_rne(acc[i][j][g]);
        __syncthreads();
        const int b = m0 >> 10, nn0 = m0 & 1023;
        const size_t vbase = (size_t)(b * 8 + h) * 65536 + nn0;
#pragma unroll
        for (int p = 0; p < 2; ++p) {
            const int d = (p << 5) + (l >> 1);
            const int c = (l & 1) << 4;
            ushort_t* dst = &Vt[vbase + (size_t)d * 1024 + c];
            *(us8*)dst       = *(const us8*)&vtile[w][d][c];
            *(us8*)(dst + 8) = *(const us8*)&vtile[w][d][c + 8];
        }
    }
}

// out-proj: fp32 C + bias
__global__ __launch_bounds__(256) void gemm_out_mfma(
    const ushort_t* __restrict__ Ah, const ushort_t* __restrict__ Al,
    const ushort_t* __restrict__ Wh, const ushort_t* __restrict__ Wl,
    const float* __restrict__ bias, float* __restrict__ C) {
    GEMM_CORE(INNER_, Ah, Al, Wh, Wl)
#pragma unroll
    for (int i = 0; i < 2; ++i)
#pragma unroll
        for (int j = 0; j < 4; ++j) {
            const int col = n0 + j * 16 + ln;
            const float bb = bias[col];
#pragma unroll
            for (int g = 0; g < 4; ++g) {
                const int token = m0 + i * 16 + quad * 4 + g;
                C[(size_t)token * DIM_ + col] = acc[i][j][g] + bb;
            }
        }
}

// ---------------------------------------------------------------------------
// MFMA kNN attention. WG = 256 thr (4 waves) = (b,h, 16 q-rows).
// bh = wg & 31  =>  all 64 blocks of a head share one XCD (K/V L2-resident).
// Phase 2 count: per-lane VALU count lc, cross-lane via 5 INDEPENDENT ballots
// of lc's bits (cnt = sum 2^b * popc(ballot(lc>>b&1))) -- kills the serialized
// 16-ballot chain that dominated r3/r4.
// ---------------------------------------------------------------------------
__global__ __launch_bounds__(256) void attn_mfma(const ushort_t* __restrict__ Qh,
                                                 const ushort_t* __restrict__ Ql,
                                                 const ushort_t* __restrict__ Kh,
                                                 const ushort_t* __restrict__ Kl,
                                                 const ushort_t* __restrict__ Vt,
                                                 ushort_t* __restrict__ Oh,
                                                 ushort_t* __restrict__ Ol) {
    __shared__ float sdots[16 * 1024];   // exactly 64 KB

    const int t    = threadIdx.x;
    const int w    = t >> 6;
    const int l    = t & 63;
    const int ln   = l & 15;
    const int quad = l >> 4;
    const int wg   = blockIdx.x;
    const int bh   = wg & 31;            // XCD-local heads
    const int i0   = (wg >> 5) << 4;

    const size_t bhoff = (size_t)bh << 16;

    // ---- Q fragments
    const ushort_t* qp  = Qh + bhoff + (size_t)(i0 + ln) * 64 + (quad << 3);
    const ushort_t* qlp = Ql + bhoff + (size_t)(i0 + ln) * 64 + (quad << 3);
    bf16x8 qh0 = *(const bf16x8*)qp;
    bf16x8 qh1 = *(const bf16x8*)(qp + 32);
    bf16x8 ql0 = *(const bf16x8*)qlp;
    bf16x8 ql1 = *(const bf16x8*)(qlp + 32);

    // ---- Phase 1: dots
    for (int tt = 0; tt < 16; ++tt) {
        const int j0 = ((w << 4) + tt) << 4;
        const ushort_t* kp  = Kh + bhoff + (size_t)(j0 + ln) * 64 + (quad << 3);
        const ushort_t* klp = Kl + bhoff + (size_t)(j0 + ln) * 64 + (quad << 3);
        bf16x8 kh0 = *(const bf16x8*)kp;
        bf16x8 kh1 = *(const bf16x8*)(kp + 32);
        bf16x8 kl0 = *(const bf16x8*)klp;
        bf16x8 kl1 = *(const bf16x8*)(klp + 32);
        f32x4 acc = {0.f, 0.f, 0.f, 0.f};
        acc = __builtin_amdgcn_mfma_f32_16x16x32_bf16(qh0, kh0, acc, 0, 0, 0);
        acc = __builtin_amdgcn_mfma_f32_16x16x32_bf16(qh1, kh1, acc, 0, 0, 0);
        acc = __builtin_amdgcn_mfma_f32_16x16x32_bf16(qh0, kl0, acc, 0, 0, 0);
        acc = __builtin_amdgcn_mfma_f32_16x16x32_bf16(qh1, kl1, acc, 0, 0, 0);
        acc = __builtin_amdgcn_mfma_f32_16x16x32_bf16(ql0, kh0, acc, 0, 0, 0);
        acc = __builtin_amdgcn_mfma_f32_16x16x32_bf16(ql1, kh1, acc, 0, 0, 0);
#pragma unroll
        for (int g = 0; g < 4; ++g) {
            const int row = (quad << 2) + g;
            sdots[(row << 10) + ((j0 + ln) ^ ((row & 7) << 2))] = acc[g] * SCALE_;
        }
    }
    __syncthreads();

    // ---- Phase 2: top-k + softmax(ref=thr) + in-place bf16 P
    ushort_t* sP = (ushort_t*)sdots;
    for (int rr = 0; rr < 4; ++rr) {
        const int r   = (w << 2) + rr;
        const int swz = (r & 7) << 2;
        const float* srow = &sdots[r << 10];
        // lane l holds keys for j = 4l + 256m + i  (m=0..3, i=0..3)
        unsigned key[16];
#pragma unroll
        for (int m = 0; m < 4; ++m) {
            f32x4 kv = *(const f32x4*)&srow[((l << 2) + (m << 8)) ^ swz];
#pragma unroll
            for (int i = 0; i < 4; ++i) key[(m << 2) + i] = f2key(kv[i]);
        }
        unsigned res = 0u;
        for (int bit = 31; bit >= 0; --bit) {
            const unsigned trial = res | (1u << bit);
            int lc = 0;
#pragma unroll
            for (int m = 0; m < 16; ++m) lc += (key[m] >= trial) ? 1 : 0;
            unsigned long long b0 = __ballot(lc & 1);
            unsigned long long b1 = __ballot(lc & 2);
            unsigned long long b2 = __ballot(lc & 4);
            unsigned long long b3 = __ballot(lc & 8);
            unsigned long long b4 = __ballot(lc & 16);
            int c = __popcll(b0) + (__popcll(b1) << 1) + (__popcll(b2) << 2) +
                    (__popcll(b3) << 3) + (__popcll(b4) << 4);
            if (c >= KK_) {
                res = trial;
                if (c == KK_) break;   // wave-uniform
            }
        }
        const float thr = key2f(res);
        float pv[16];
        float lsum = 0.f;
#pragma unroll
        for (int m = 0; m < 16; ++m) {
            float p = (key[m] >= res) ? __expf(key2f(key[m]) - thr) : 0.f;
            pv[m] = p;
            lsum += p;
        }
#pragma unroll
        for (int off = 32; off; off >>= 1) lsum += __shfl_xor(lsum, off, 64);
        const float inv = 1.f / lsum;
        // store P (bf16, phase-3 layout): j = 4l + 256m + i
        //   g = (j>>3) ^ (r&7) = ((l>>1) + 32m) ^ (r&7);  j&7 = (l&1)*4 + i
#pragma unroll
        for (int m = 0; m < 4; ++m) {
            const int g = ((l >> 1) + (m << 5)) ^ (r & 7);
            ushort4 pk = make_ushort4(bf16_rne(pv[(m << 2) + 0] * inv),
                                      bf16_rne(pv[(m << 2) + 1] * inv),
                                      bf16_rne(pv[(m << 2) + 2] * inv),
                                      bf16_rne(pv[(m << 2) + 3] * inv));
            *(ushort4*)&sP[(r << 11) + (g << 3) + ((l & 1) << 2)] = pk;
        }
    }
    __syncthreads();

    // ---- Phase 3: O = P @ V
    f32x4 oacc = {0.f, 0.f, 0.f, 0.f};
    const ushort_t* vp = Vt + bhoff + (size_t)((w << 4) + ln) * 1024 + (quad << 3);
    const int prow = ln << 11;
    const int rsw  = ln & 7;
    for (int j0 = 0; j0 < 1024; j0 += 32) {
        const int g = (j0 >> 3) + quad;
        bf16x8 af = *(const bf16x8*)&sP[prow + ((g ^ rsw) << 3)];
        bf16x8 bv = *(const bf16x8*)(vp + j0);
        oacc = __builtin_amdgcn_mfma_f32_16x16x32_bf16(af, bv, oacc, 0, 0, 0);
    }
    const int b = bh >> 3, h = bh & 7;
    const size_t obase =
        ((size_t)(b << 10) + i0 + (quad << 2)) * 512 + (h << 6) + (w << 4) + ln;
#pragma unroll
    for (int g = 0; g < 4; ++g) {
        const float v = oacc[g];
        ushort_t hb = bf16_rne(v);
        Oh[obase + (size_t)g * 512] = hb;
        Ol[obase + (size_t)g * 512] = bf16_rne(v - bf16_f(hb));
    }
}

extern "C" void kernel_launch(void* const* d_in, const int* in_sizes, int n_in,
                              void* d_out, int out_size, void* d_ws, size_t ws_size,
                              hipStream_t stream) {
    const float* x     = (const float*)d_in[0];
    const float* w_qkv = (const float*)d_in[1];
    const float* w_out = (const float*)d_in[2];
    const float* b_out = (const float*)d_in[3];
    float*       out   = (float*)d_out;

    const size_t XN  = (size_t)4096 * 512;
    const size_t WQT = (size_t)1536 * 512;
    const size_t WOT = (size_t)512 * 512;
    const size_t QK  = (size_t)32 * 1024 * 64;

    ushort_t* p    = (ushort_t*)d_ws;
    ushort_t* Xh   = p;            p += XN;
    ushort_t* Xl   = p;            p += XN;
    ushort_t* WqTh = p;            p += WQT;
    ushort_t* WqTl = p;            p += WQT;
    ushort_t* WoTh = p;            p += WOT;
    ushort_t* WoTl = p;            p += WOT;
    ushort_t* Qh   = p;            p += QK;
    ushort_t* Ql   = p;            p += QK;
    ushort_t* Kh   = p;            p += QK;
    ushort_t* Kl   = p;            p += QK;
    ushort_t* Vt   = p;            p += QK;
    // O aliases X (x is dead after gemm_qkv_mfma) — total exactly 32 MiB
    ushort_t* Oh = Xh;
    ushort_t* Ol = Xl;

    conv_split<<<dim3((XN / 4 + 255) / 256), 256, 0, stream>>>(x, Xh, Xl, (int)(XN / 4));
    conv_wT<<<dim3(TRIPLE_ / 32, DIM_ / 32), 256, 0, stream>>>(w_qkv, WqTh, WqTl, DIM_, TRIPLE_);
    conv_wT<<<dim3(DIM_ / 32, INNER_ / 32), 256, 0, stream>>>(w_out, WoTh, WoTl, INNER_, DIM_);

    // blockIdx.x = m-block so A tiles are XCD-local
    gemm_qkv_mfma<<<dim3(4096 / 128, TRIPLE_ / 64), 256, 0, stream>>>(
        Xh, Xl, WqTh, WqTl, Qh, Ql, Kh, Kl, Vt);

    attn_mfma<<<dim3(B_ * H_ * (N_ / 16)), 256, 0, stream>>>(Qh, Ql, Kh, Kl, Vt, Oh, Ol);

    gemm_out_mfma<<<dim3(4096 / 128, DIM_ / 64), 256, 0, stream>>>(
        Oh, Ol, WoTh, WoTl, b_out, out);
}

// Round 6
// 285.178 us; speedup vs baseline: 6.8888x; 1.1099x over previous
//
#include <hip/hip_runtime.h>
#include <cstddef>

#define B_      4
#define N_      1024
#define DIM_    512
#define H_      8
#define D_      64
#define INNER_  512
#define TRIPLE_ 1536
#define KK_     716        // int(1024 * 0.7)
#define SCALE_  0.125f     // 64^-0.5

typedef short bf16x8 __attribute__((ext_vector_type(8)));
typedef float f32x4  __attribute__((ext_vector_type(4)));
typedef unsigned short ushort_t;
typedef ushort_t us8 __attribute__((ext_vector_type(8)));

__device__ __forceinline__ unsigned short bf16_rne(float f) {
    unsigned u = __float_as_uint(f);
    return (unsigned short)((u + 0x7FFFu + ((u >> 16) & 1u)) >> 16);
}
__device__ __forceinline__ float bf16_f(unsigned short s) {
    return __uint_as_float((unsigned)s << 16);
}
// order-preserving float->uint key (descending float == descending uint)
__device__ __forceinline__ unsigned f2key(float f) {
    unsigned u = __float_as_uint(f);
    return u ^ ((u & 0x80000000u) ? 0xFFFFFFFFu : 0x80000000u);
}
__device__ __forceinline__ float key2f(unsigned k) {
    unsigned u = (k & 0x80000000u) ? (k ^ 0x80000000u) : ~k;
    return __uint_as_float(u);
}
// load 8 contiguous f32, emit hi/lo bf16 fragments
__device__ __forceinline__ void split8(const float* __restrict__ src,
                                       bf16x8& h8, bf16x8& l8) {
    float4 a = *(const float4*)src;
    float4 b = *(const float4*)(src + 4);
    float v[8] = {a.x, a.y, a.z, a.w, b.x, b.y, b.z, b.w};
#pragma unroll
    for (int i = 0; i < 8; ++i) {
        ushort_t hb = bf16_rne(v[i]);
        h8[i] = (short)hb;
        l8[i] = (short)bf16_rne(v[i] - bf16_f(hb));
    }
}

// ---------------------------------------------------------------------------
// W[K][Nn] f32  ->  Th[Nn][K], Tl[Nn][K] bf16 (transpose + split), 32x32 tiles
// ---------------------------------------------------------------------------
__global__ __launch_bounds__(256) void conv_wT(const float* __restrict__ W,
                                               ushort_t* __restrict__ Th,
                                               ushort_t* __restrict__ Tl,
                                               int K, int Nn) {
    __shared__ float tile[32][33];
    const int nb = blockIdx.x * 32, kb = blockIdx.y * 32;
    const int tx = threadIdx.x & 31, ty = threadIdx.x >> 5;   // ty 0..7
    for (int yy = ty; yy < 32; yy += 8)
        tile[yy][tx] = W[(size_t)(kb + yy) * Nn + nb + tx];
    __syncthreads();
    for (int yy = ty; yy < 32; yy += 8) {
        float v = tile[tx][yy];
        ushort_t hb = bf16_rne(v);
        size_t idx = (size_t)(nb + yy) * K + kb + tx;
        Th[idx] = hb;
        Tl[idx] = bf16_rne(v - bf16_f(hb));
    }
}

// ---------------------------------------------------------------------------
// Split-bf16 MFMA GEMM core (bf16 A inputs): wave = 32x64, WG = 4 waves.
// ---------------------------------------------------------------------------
#define GEMM_CORE(K_DIM, AH, AL, BH, BL)                                     \
    const int t = threadIdx.x, w = t >> 6, l = t & 63;                       \
    const int ln = l & 15, quad = l >> 4;                                    \
    const int n0 = blockIdx.y * 64;                                          \
    const int m0 = blockIdx.x * 128 + w * 32;                                \
    f32x4 acc[2][4] = {};                                                    \
    {                                                                        \
        const size_t arow0 = (size_t)(m0 + ln) * (K_DIM);                    \
        const size_t arow1 = (size_t)(m0 + 16 + ln) * (K_DIM);               \
        for (int k0 = 0; k0 < (K_DIM); k0 += 32) {                           \
            const int ko = k0 + quad * 8;                                    \
            bf16x8 ah0 = *(const bf16x8*)&AH[arow0 + ko];                    \
            bf16x8 al0 = *(const bf16x8*)&AL[arow0 + ko];                    \
            bf16x8 ah1 = *(const bf16x8*)&AH[arow1 + ko];                    \
            bf16x8 al1 = *(const bf16x8*)&AL[arow1 + ko];                    \
            _Pragma("unroll")                                                \
            for (int j = 0; j < 4; ++j) {                                    \
                const size_t brow = (size_t)(n0 + j * 16 + ln) * (K_DIM) + ko; \
                bf16x8 bh = *(const bf16x8*)&BH[brow];                       \
                bf16x8 bl = *(const bf16x8*)&BL[brow];                       \
                acc[0][j] = __builtin_amdgcn_mfma_f32_16x16x32_bf16(ah0, bh, acc[0][j], 0, 0, 0); \
                acc[0][j] = __builtin_amdgcn_mfma_f32_16x16x32_bf16(al0, bh, acc[0][j], 0, 0, 0); \
                acc[0][j] = __builtin_amdgcn_mfma_f32_16x16x32_bf16(ah0, bl, acc[0][j], 0, 0, 0); \
                acc[1][j] = __builtin_amdgcn_mfma_f32_16x16x32_bf16(ah1, bh, acc[1][j], 0, 0, 0); \
                acc[1][j] = __builtin_amdgcn_mfma_f32_16x16x32_bf16(al1, bh, acc[1][j], 0, 0, 0); \
                acc[1][j] = __builtin_amdgcn_mfma_f32_16x16x32_bf16(ah1, bl, acc[1][j], 0, 0, 0); \
            }                                                                \
        }                                                                    \
    }

// qkv GEMM: reads x fp32 directly, splits A frags in-register (no conv_split).
// V blocks transpose through LDS so Vt writes are full 64B lines.
__global__ __launch_bounds__(256) void gemm_qkv_mfma(
    const float* __restrict__ X,
    const ushort_t* __restrict__ Wh, const ushort_t* __restrict__ Wl,
    ushort_t* __restrict__ Qh, ushort_t* __restrict__ Ql,
    ushort_t* __restrict__ Kh, ushort_t* __restrict__ Kl,
    ushort_t* __restrict__ Vt) {
    __shared__ ushort_t vtile[4][64][40];   // 20 KB
    const int t = threadIdx.x, w = t >> 6, l = t & 63;
    const int ln = l & 15, quad = l >> 4;
    const int n0 = blockIdx.y * 64;
    const int m0 = blockIdx.x * 128 + w * 32;
    f32x4 acc[2][4] = {};
    {
        const size_t xrow0 = (size_t)(m0 + ln) * DIM_;
        const size_t xrow1 = (size_t)(m0 + 16 + ln) * DIM_;
        for (int k0 = 0; k0 < DIM_; k0 += 32) {
            const int ko = k0 + quad * 8;
            bf16x8 ah0, al0, ah1, al1;
            split8(&X[xrow0 + ko], ah0, al0);
            split8(&X[xrow1 + ko], ah1, al1);
#pragma unroll
            for (int j = 0; j < 4; ++j) {
                const size_t brow = (size_t)(n0 + j * 16 + ln) * DIM_ + ko;
                bf16x8 bh = *(const bf16x8*)&Wh[brow];
                bf16x8 bl = *(const bf16x8*)&Wl[brow];
                acc[0][j] = __builtin_amdgcn_mfma_f32_16x16x32_bf16(ah0, bh, acc[0][j], 0, 0, 0);
                acc[0][j] = __builtin_amdgcn_mfma_f32_16x16x32_bf16(al0, bh, acc[0][j], 0, 0, 0);
                acc[0][j] = __builtin_amdgcn_mfma_f32_16x16x32_bf16(ah0, bl, acc[0][j], 0, 0, 0);
                acc[1][j] = __builtin_amdgcn_mfma_f32_16x16x32_bf16(ah1, bh, acc[1][j], 0, 0, 0);
                acc[1][j] = __builtin_amdgcn_mfma_f32_16x16x32_bf16(al1, bh, acc[1][j], 0, 0, 0);
                acc[1][j] = __builtin_amdgcn_mfma_f32_16x16x32_bf16(ah1, bl, acc[1][j], 0, 0, 0);
            }
        }
    }
    const int sec = n0 >> 9;
    const int h   = (n0 >> 6) & 7;
    if (sec < 2) {
#pragma unroll
        for (int i = 0; i < 2; ++i)
#pragma unroll
            for (int j = 0; j < 4; ++j)
#pragma unroll
                for (int g = 0; g < 4; ++g) {
                    const int token = m0 + i * 16 + quad * 4 + g;
                    const int d = j * 16 + ln;
                    const int b = token >> 10, nn = token & 1023;
                    const float v = acc[i][j][g];
                    size_t base = ((size_t)(b * 8 + h) * 1024 + nn) * 64 + d;
                    ushort_t hb = bf16_rne(v);
                    ushort_t lb = bf16_rne(v - bf16_f(hb));
                    if (sec == 0) { Qh[base] = hb; Ql[base] = lb; }
                    else          { Kh[base] = hb; Kl[base] = lb; }
                }
    } else {
#pragma unroll
        for (int i = 0; i < 2; ++i)
#pragma unroll
            for (int j = 0; j < 4; ++j)
#pragma unroll
                for (int g = 0; g < 4; ++g)
                    vtile[w][j * 16 + ln][i * 16 + quad * 4 + g] = bf16_rne(acc[i][j][g]);
        __syncthreads();
        const int b = m0 >> 10, nn0 = m0 & 1023;
        const size_t vbase = (size_t)(b * 8 + h) * 65536 + nn0;
#pragma unroll
        for (int p = 0; p < 2; ++p) {
            const int d = (p << 5) + (l >> 1);
            const int c = (l & 1) << 4;
            ushort_t* dst = &Vt[vbase + (size_t)d * 1024 + c];
            *(us8*)dst       = *(const us8*)&vtile[w][d][c];
            *(us8*)(dst + 8) = *(const us8*)&vtile[w][d][c + 8];
        }
    }
}

// out-proj: fp32 C + bias
__global__ __launch_bounds__(256) void gemm_out_mfma(
    const ushort_t* __restrict__ Ah, const ushort_t* __restrict__ Al,
    const ushort_t* __restrict__ Wh, const ushort_t* __restrict__ Wl,
    const float* __restrict__ bias, float* __restrict__ C) {
    GEMM_CORE(INNER_, Ah, Al, Wh, Wl)
#pragma unroll
    for (int i = 0; i < 2; ++i)
#pragma unroll
        for (int j = 0; j < 4; ++j) {
            const int col = n0 + j * 16 + ln;
            const float bb = bias[col];
#pragma unroll
            for (int g = 0; g < 4; ++g) {
                const int token = m0 + i * 16 + quad * 4 + g;
                C[(size_t)token * DIM_ + col] = acc[i][j][g] + bb;
            }
        }
}

// ---------------------------------------------------------------------------
// MFMA kNN attention. WG = 512 thr (8 waves) = (b,h, 16 q-rows).
// bh = wg & 31 => all 64 blocks of a head share one XCD (K/V L2-resident).
// 8 waves double occupancy vs r5 (16 waves/CU) to hide the phase-2
// ballot-chain latency. Phase 3 splits the j-range across wave pairs and
// merges partials via LDS.
// ---------------------------------------------------------------------------
__global__ __launch_bounds__(512) void attn_mfma(const ushort_t* __restrict__ Qh,
                                                 const ushort_t* __restrict__ Ql,
                                                 const ushort_t* __restrict__ Kh,
                                                 const ushort_t* __restrict__ Kl,
                                                 const ushort_t* __restrict__ Vt,
                                                 ushort_t* __restrict__ Oh,
                                                 ushort_t* __restrict__ Ol) {
    __shared__ float sdots[16 * 1024];        // 64 KB
    __shared__ float spartial[4][16][17];     // 4.25 KB j-split merge buffer

    const int t    = threadIdx.x;
    const int w    = t >> 6;        // wave 0..7
    const int l    = t & 63;
    const int ln   = l & 15;
    const int quad = l >> 4;
    const int wg   = blockIdx.x;
    const int bh   = wg & 31;       // XCD-local heads
    const int i0   = (wg >> 5) << 4;

    const size_t bhoff = (size_t)bh << 16;

    // ---- Q fragments (same for all waves)
    const ushort_t* qp  = Qh + bhoff + (size_t)(i0 + ln) * 64 + (quad << 3);
    const ushort_t* qlp = Ql + bhoff + (size_t)(i0 + ln) * 64 + (quad << 3);
    bf16x8 qh0 = *(const bf16x8*)qp;
    bf16x8 qh1 = *(const bf16x8*)(qp + 32);
    bf16x8 ql0 = *(const bf16x8*)qlp;
    bf16x8 ql1 = *(const bf16x8*)(qlp + 32);

    // ---- Phase 1: dots. wave w covers j in [w*128, w*128+128)
    for (int tt = 0; tt < 8; ++tt) {
        const int j0 = ((w << 3) + tt) << 4;
        const ushort_t* kp  = Kh + bhoff + (size_t)(j0 + ln) * 64 + (quad << 3);
        const ushort_t* klp = Kl + bhoff + (size_t)(j0 + ln) * 64 + (quad << 3);
        bf16x8 kh0 = *(const bf16x8*)kp;
        bf16x8 kh1 = *(const bf16x8*)(kp + 32);
        bf16x8 kl0 = *(const bf16x8*)klp;
        bf16x8 kl1 = *(const bf16x8*)(klp + 32);
        f32x4 acc = {0.f, 0.f, 0.f, 0.f};
        acc = __builtin_amdgcn_mfma_f32_16x16x32_bf16(qh0, kh0, acc, 0, 0, 0);
        acc = __builtin_amdgcn_mfma_f32_16x16x32_bf16(qh1, kh1, acc, 0, 0, 0);
        acc = __builtin_amdgcn_mfma_f32_16x16x32_bf16(qh0, kl0, acc, 0, 0, 0);
        acc = __builtin_amdgcn_mfma_f32_16x16x32_bf16(qh1, kl1, acc, 0, 0, 0);
        acc = __builtin_amdgcn_mfma_f32_16x16x32_bf16(ql0, kh0, acc, 0, 0, 0);
        acc = __builtin_amdgcn_mfma_f32_16x16x32_bf16(ql1, kh1, acc, 0, 0, 0);
#pragma unroll
        for (int g = 0; g < 4; ++g) {
            const int row = (quad << 2) + g;
            sdots[(row << 10) + ((j0 + ln) ^ ((row & 7) << 2))] = acc[g] * SCALE_;
        }
    }
    __syncthreads();

    // ---- Phase 2: top-k + softmax(ref=thr) + in-place bf16 P (2 rows/wave)
    ushort_t* sP = (ushort_t*)sdots;
    for (int rr = 0; rr < 2; ++rr) {
        const int r   = (w << 1) + rr;
        const int swz = (r & 7) << 2;
        const float* srow = &sdots[r << 10];
        // lane l holds keys for j = 4l + 256m + i  (m=0..3, i=0..3)
        unsigned key[16];
#pragma unroll
        for (int m = 0; m < 4; ++m) {
            f32x4 kv = *(const f32x4*)&srow[((l << 2) + (m << 8)) ^ swz];
#pragma unroll
            for (int i = 0; i < 4; ++i) key[(m << 2) + i] = f2key(kv[i]);
        }
        unsigned res = 0u;
        for (int bit = 31; bit >= 0; --bit) {
            const unsigned trial = res | (1u << bit);
            int lc = 0;
#pragma unroll
            for (int m = 0; m < 16; ++m) lc += (key[m] >= trial) ? 1 : 0;
            unsigned long long b0 = __ballot(lc & 1);
            unsigned long long b1 = __ballot(lc & 2);
            unsigned long long b2 = __ballot(lc & 4);
            unsigned long long b3 = __ballot(lc & 8);
            unsigned long long b4 = __ballot(lc & 16);
            int c = __popcll(b0) + (__popcll(b1) << 1) + (__popcll(b2) << 2) +
                    (__popcll(b3) << 3) + (__popcll(b4) << 4);
            if (c >= KK_) {
                res = trial;
                if (c == KK_) break;   // wave-uniform
            }
        }
        const float thr = key2f(res);
        float pv[16];
        float lsum = 0.f;
#pragma unroll
        for (int m = 0; m < 16; ++m) {
            float p = (key[m] >= res) ? __expf(key2f(key[m]) - thr) : 0.f;
            pv[m] = p;
            lsum += p;
        }
#pragma unroll
        for (int off = 32; off; off >>= 1) lsum += __shfl_xor(lsum, off, 64);
        const float inv = 1.f / lsum;
        // store P (bf16, phase-3 layout): j = 4l + 256m + i
#pragma unroll
        for (int m = 0; m < 4; ++m) {
            const int g = ((l >> 1) + (m << 5)) ^ (r & 7);
            ushort4 pk = make_ushort4(bf16_rne(pv[(m << 2) + 0] * inv),
                                      bf16_rne(pv[(m << 2) + 1] * inv),
                                      bf16_rne(pv[(m << 2) + 2] * inv),
                                      bf16_rne(pv[(m << 2) + 3] * inv));
            *(ushort4*)&sP[(r << 11) + (g << 3) + ((l & 1) << 2)] = pk;
        }
    }
    __syncthreads();

    // ---- Phase 3: O = P @ V.  wave w: d-block (w&3), j-half (w&4 ? hi : lo)
    const int dblk  = w & 3;
    const int jbase = (w & 4) << 7;   // 0 or 512
    f32x4 oacc = {0.f, 0.f, 0.f, 0.f};
    const ushort_t* vp =
        Vt + bhoff + (size_t)((dblk << 4) + ln) * 1024 + (quad << 3) + jbase;
    const int prow = ln << 11;
    const int rsw  = ln & 7;
    for (int j0 = 0; j0 < 512; j0 += 32) {
        const int g = ((jbase + j0) >> 3) + quad;
        bf16x8 af = *(const bf16x8*)&sP[prow + ((g ^ rsw) << 3)];
        bf16x8 bv = *(const bf16x8*)(vp + j0);
        oacc = __builtin_amdgcn_mfma_f32_16x16x32_bf16(af, bv, oacc, 0, 0, 0);
    }
    if (w & 4) {
#pragma unroll
        for (int g = 0; g < 4; ++g)
            spartial[dblk][(quad << 2) + g][ln] = oacc[g];
    }
    __syncthreads();
    if (!(w & 4)) {
        const int b = bh >> 3, h = bh & 7;
        const size_t obase =
            ((size_t)(b << 10) + i0 + (quad << 2)) * 512 + (h << 6) + (dblk << 4) + ln;
#pragma unroll
        for (int g = 0; g < 4; ++g) {
            const float v = oacc[g] + spartial[dblk][(quad << 2) + g][ln];
            ushort_t hb = bf16_rne(v);
            Oh[obase + (size_t)g * 512] = hb;
            Ol[obase + (size_t)g * 512] = bf16_rne(v - bf16_f(hb));
        }
    }
}

extern "C" void kernel_launch(void* const* d_in, const int* in_sizes, int n_in,
                              void* d_out, int out_size, void* d_ws, size_t ws_size,
                              hipStream_t stream) {
    const float* x     = (const float*)d_in[0];
    const float* w_qkv = (const float*)d_in[1];
    const float* w_out = (const float*)d_in[2];
    const float* b_out = (const float*)d_in[3];
    float*       out   = (float*)d_out;

    const size_t ON  = (size_t)4096 * 512;
    const size_t WQT = (size_t)1536 * 512;
    const size_t WOT = (size_t)512 * 512;
    const size_t QK  = (size_t)32 * 1024 * 64;

    ushort_t* p    = (ushort_t*)d_ws;
    ushort_t* Oh   = p;            p += ON;
    ushort_t* Ol   = p;            p += ON;
    ushort_t* WqTh = p;            p += WQT;
    ushort_t* WqTl = p;            p += WQT;
    ushort_t* WoTh = p;            p += WOT;
    ushort_t* WoTl = p;            p += WOT;
    ushort_t* Qh   = p;            p += QK;
    ushort_t* Ql   = p;            p += QK;
    ushort_t* Kh   = p;            p += QK;
    ushort_t* Kl   = p;            p += QK;
    ushort_t* Vt   = p;            p += QK;   // total exactly 32 MiB

    conv_wT<<<dim3(TRIPLE_ / 32, DIM_ / 32), 256, 0, stream>>>(w_qkv, WqTh, WqTl, DIM_, TRIPLE_);
    conv_wT<<<dim3(DIM_ / 32, INNER_ / 32), 256, 0, stream>>>(w_out, WoTh, WoTl, INNER_, DIM_);

    // blockIdx.x = m-block so A tiles are XCD-local
    gemm_qkv_mfma<<<dim3(4096 / 128, TRIPLE_ / 64), 256, 0, stream>>>(
        x, WqTh, WqTl, Qh, Ql, Kh, Kl, Vt);

    attn_mfma<<<dim3(B_ * H_ * (N_ / 16)), 512, 0, stream>>>(Qh, Ql, Kh, Kl, Vt, Oh, Ol);

    gemm_out_mfma<<<dim3(4096 / 128, DIM_ / 64), 256, 0, stream>>>(
        Oh, Ol, WoTh, WoTl, b_out, out);
}